// Round 5
// baseline (238.610 us; speedup 1.0000x reference)
//
#include <hip/hip_runtime.h>
#include <math.h>

typedef short short8 __attribute__((ext_vector_type(8)));
typedef float f32x4 __attribute__((ext_vector_type(4)));
typedef float f32x16 __attribute__((ext_vector_type(16)));

__device__ __forceinline__ float2 cmul(float2 a, float2 b) {
    return make_float2(a.x * b.x - a.y * b.y, a.x * b.y + a.y * b.x);
}

__device__ __forceinline__ ushort f2bf(float f) {
    uint u = __float_as_uint(f);
    uint r = (u + 0x7FFFu + ((u >> 16) & 1u)) >> 16;
    return (ushort)r;
}

// ---- prep: conv2 weights -> wt2[tap][icg][oc][ic8] bf16 ; fc1 weights -> bf16 ----
__global__ __launch_bounds__(256) void prep_kernel(
    const float* __restrict__ c2w, const float* __restrict__ f1w,
    ushort* __restrict__ wt2, ushort* __restrict__ wf1)
{
    int i = blockIdx.x * 256 + threadIdx.x;
    if (i < 18432) {
        int icl = i & 7;
        int t = i >> 3;
        int oc = t & 63;
        int t2 = t >> 6;
        int icg = t2 & 3;
        int tap = t2 >> 2;
        int ic = icg * 8 + icl;
        wt2[i] = f2bf(c2w[(oc * 32 + ic) * 9 + tap]);
    } else if (i < 18432 + 1179648) {
        int j = i - 18432;
        wf1[j] = f2bf(f1w[j]);
    }
}

// ---- banded fused conv1+conv2+pool: one block per (image, band of 8 conv rows) ----
// 384 thr = 6 waves; per block: conv1 rows r0..r0+9 in LDS (16.6 KB), then
// 9-tap GEMM(64oc x 192px x 32ic); wave = one 8x4 px region; shfl 2x2 maxpool.
__global__ __launch_bounds__(384, 4) void conv2_banded(
    const float* __restrict__ x, const float* __restrict__ w1,
    const float* __restrict__ b1, const ushort* __restrict__ wt2,
    const float* __restrict__ c2b, ushort* __restrict__ pooled)
{
    __shared__ ushort h1s[8320];     // [icg 4][px 260][ic8] bf16, 16,640 B
    __shared__ float xs[336];        // 12 x 28 input rows
    __shared__ float w1s[288];
    __shared__ float b1s[32];
    __shared__ float b2s[64];
    int bx = blockIdx.x;
    int b = bx / 3;
    int band = bx % 3;
    int r0 = band * 8;               // conv-row base of this band
    int tid = threadIdx.x;

    // stage: x rows r0..r0+11, conv1 w/b, conv2 bias
    if (tid < 84) {
        ((uint4*)xs)[tid] = ((const uint4*)(x + (size_t)b * 784 + r0 * 28))[tid];
    } else if (tid < 156) {
        ((uint4*)w1s)[tid - 84] = ((const uint4*)w1)[tid - 84];
    } else if (tid < 164) {
        ((uint4*)b1s)[tid - 156] = ((const uint4*)b1)[tid - 156];
    } else if (tid < 180) {
        ((uint4*)b2s)[tid - 164] = ((const uint4*)c2b)[tid - 164];
    }
    __syncthreads();

    // conv1 + relu -> h1s, local rows 0..9, cols 0..25 (1040 tasks)
    for (int task = tid; task < 1040; task += 384) {
        int icg = task & 3;
        int p = task >> 2;
        int row = p / 26, col = p % 26;
        float in9[9];
#pragma unroll
        for (int ky = 0; ky < 3; ++ky)
#pragma unroll
            for (int kx = 0; kx < 3; ++kx)
                in9[ky * 3 + kx] = xs[(row + ky) * 28 + col + kx];
        short8 ov;
#pragma unroll
        for (int o = 0; o < 8; ++o) {
            int oc = icg * 8 + o;
            float acc = b1s[oc];
#pragma unroll
            for (int k = 0; k < 9; ++k) acc = fmaf(in9[k], w1s[oc * 9 + k], acc);
            ov[o] = (short)f2bf(fmaxf(acc, 0.f));
        }
        *(short8*)&h1s[(icg * 260 + p) * 8] = ov;
    }
    __syncthreads();

    int wid = tid >> 6;
    int lane = tid & 63;
    int lo = lane & 31;
    int hi = lane >> 5;
    int rx = wid % 3, ry = wid / 3;          // region: 8 wide x 4 tall
    int xcoord = rx * 8 + (lo & 7);
    int ycoord = ry * 4 + (lo >> 3);         // band-local conv row
    int pbase = ycoord * 26 + xcoord;        // short8 units within one icg plane

    const short8* hs8 = (const short8*)h1s;
    const short8* wt8 = (const short8*)wt2;

    f32x16 acc0 = (f32x16)0.f, acc1 = (f32x16)0.f;

    // A-fragment double-buffer from L2-hot global
    short8 Ac[2][2];
#pragma unroll
    for (int ks = 0; ks < 2; ++ks)
#pragma unroll
        for (int mt = 0; mt < 2; ++mt)
            Ac[ks][mt] = wt8[(ks * 2 + hi) * 64 + mt * 32 + lo];

#pragma unroll
    for (int tap = 0; tap < 9; ++tap) {
        int tn = tap < 8 ? tap + 1 : tap;
        short8 An[2][2];
#pragma unroll
        for (int ks = 0; ks < 2; ++ks)
#pragma unroll
            for (int mt = 0; mt < 2; ++mt)
                An[ks][mt] = wt8[(tn * 4 + ks * 2 + hi) * 64 + mt * 32 + lo];
        int off = (tap / 3) * 26 + (tap % 3);
#pragma unroll
        for (int ks = 0; ks < 2; ++ks) {
            short8 bf = hs8[(ks * 2 + hi) * 260 + pbase + off];
            acc0 = __builtin_amdgcn_mfma_f32_32x32x16_bf16(Ac[ks][0], bf, acc0, 0, 0, 0);
            acc1 = __builtin_amdgcn_mfma_f32_32x32x16_bf16(Ac[ks][1], bf, acc1, 0, 0, 0);
        }
#pragma unroll
        for (int ks = 0; ks < 2; ++ks)
#pragma unroll
            for (int mt = 0; mt < 2; ++mt) Ac[ks][mt] = An[ks][mt];
    }

    // epilogue: bias + relu + 2x2 maxpool via shfl, packed bf16-pair stores
    ushort* pout = pooled + (size_t)b * 9216;
    int prow = band * 4 + ry * 2 + (lo >> 4);
    int pcol = rx * 4 + ((lo >> 1) & 3);
    bool st = (lo & 0xB) == 0;               // lo in {0,4,16,20}
#pragma unroll
    for (int mt = 0; mt < 2; ++mt) {
#pragma unroll
        for (int r = 0; r < 16; ++r) {
            int oc = mt * 32 + (r & 3) + 8 * (r >> 2) + 4 * hi;
            float v = (mt ? acc1[r] : acc0[r]) + b2s[oc];
            v = fmaxf(v, 0.f);
            float m = fmaxf(v, __shfl_xor(v, 1, 64));
            m = fmaxf(m, __shfl_xor(m, 8, 64));
            float mp = __shfl_xor(m, 2, 64);
            if (st) {
                uint pk = (uint)f2bf(m) | ((uint)f2bf(mp) << 16);
                *(uint*)&pout[oc * 144 + prow * 12 + pcol] = pk;
            }
        }
    }
}

// ---- fc1 MFMA: pooled[2048,9216]bf16 x wf1[128,9216]bf16^T, 4-way K-split ----
__global__ __launch_bounds__(256) void fc1_mfma(
    const ushort* __restrict__ pooled, const ushort* __restrict__ wf1,
    float* __restrict__ part)
{
    int bx = blockIdx.x, by = blockIdx.y;
    int tid = threadIdx.x;
    int wid = tid >> 6, lane = tid & 63;
    int lo = lane & 15, hi = lane >> 4;
    int m0 = bx * 32;
    int kb = by * 2304;

    f32x4 acc[2][2];
#pragma unroll
    for (int mt = 0; mt < 2; ++mt)
#pragma unroll
        for (int j = 0; j < 2; ++j) acc[mt][j] = (f32x4)0.f;

    const ushort* arow0 = pooled + (size_t)(m0 + lo) * 9216 + kb + hi * 8;
    const ushort* arow1 = arow0 + 16 * 9216;
    const ushort* brow0 = wf1 + (size_t)(wid * 32 + lo) * 9216 + kb + hi * 8;
    const ushort* brow1 = brow0 + 16 * 9216;

    for (int kt = 0; kt < 72; ++kt) {
        short8 a0 = *(const short8*)(arow0 + kt * 32);
        short8 a1 = *(const short8*)(arow1 + kt * 32);
        short8 b0 = *(const short8*)(brow0 + kt * 32);
        short8 b1 = *(const short8*)(brow1 + kt * 32);
        acc[0][0] = __builtin_amdgcn_mfma_f32_16x16x32_bf16(a0, b0, acc[0][0], 0, 0, 0);
        acc[1][0] = __builtin_amdgcn_mfma_f32_16x16x32_bf16(a1, b0, acc[1][0], 0, 0, 0);
        acc[0][1] = __builtin_amdgcn_mfma_f32_16x16x32_bf16(a0, b1, acc[0][1], 0, 0, 0);
        acc[1][1] = __builtin_amdgcn_mfma_f32_16x16x32_bf16(a1, b1, acc[1][1], 0, 0, 0);
    }
    float* pp = part + (size_t)by * 262144;
#pragma unroll
    for (int mt = 0; mt < 2; ++mt)
#pragma unroll
        for (int j = 0; j < 2; ++j)
#pragma unroll
            for (int r = 0; r < 4; ++r)
                pp[(m0 + mt * 16 + hi * 4 + r) * 128 + wid * 32 + j * 16 + lo] = acc[mt][j][r];
}

__global__ __launch_bounds__(256) void fc1_reduce_kernel(
    const float* __restrict__ part, const float* __restrict__ bias,
    float* __restrict__ outp)
{
    int idx = blockIdx.x * 256 + threadIdx.x;   // < 262144
    float s = 0.f;
#pragma unroll
    for (int ks = 0; ks < 4; ++ks) s += part[ks * 262144 + idx];
    outp[idx] = fmaxf(s + bias[idx & 127], 0.f);
}

// ---- fc2 + sigmoid*2pi -> angles[2048,10] ----
__global__ __launch_bounds__(256) void fc2_kernel(
    const float* __restrict__ h, const float* __restrict__ w,
    const float* __restrict__ bias, float* __restrict__ ang)
{
    int idx = blockIdx.x * 256 + threadIdx.x;
    if (idx >= 20480) return;
    int b = idx / 10, n = idx % 10;
    const float* hp = h + b * 128;
    const float* wp = w + n * 128;
    float s = bias[n];
    for (int k = 0; k < 128; ++k) s = fmaf(hp[k], wp[k], s);
    ang[idx] = 6.28318530718f / (1.f + expf(-s));
}

// ---------------- quantum circuit + <Y_k> + log_softmax ----------------
__device__ __forceinline__ void apply_rot(float2* s, int p, float phi, float th,
                                          float om, int tid)
{
    float c, sn; sincosf(0.5f * th, &sn, &c);
    float A = 0.5f * (phi + om), Bv = 0.5f * (phi - om);
    float cA, sA; sincosf(A, &sA, &cA);
    float cB, sB; sincosf(Bv, &sB, &cB);
    float2 m00 = make_float2(cA * c, -sA * c);
    float2 m01 = make_float2(-cB * sn, -sB * sn);
    float2 m10 = make_float2(cB * sn, -sB * sn);
    float2 m11 = make_float2(cA * c, sA * c);
    for (int q = tid; q < 512; q += 256) {
        int i0 = ((q >> p) << (p + 1)) | (q & ((1 << p) - 1));
        int i1 = i0 | (1 << p);
        float2 aa = s[i0], bb = s[i1];
        s[i0] = make_float2(m00.x * aa.x - m00.y * aa.y + m01.x * bb.x - m01.y * bb.y,
                            m00.x * aa.y + m00.y * aa.x + m01.x * bb.y + m01.y * bb.x);
        s[i1] = make_float2(m10.x * aa.x - m10.y * aa.y + m11.x * bb.x - m11.y * bb.y,
                            m10.x * aa.y + m10.y * aa.x + m11.x * bb.y + m11.y * bb.x);
    }
}

__global__ __launch_bounds__(256) void quantum_kernel(
    const float* __restrict__ ang, const float* __restrict__ theta0,
    const float* __restrict__ theta_rz, const float* __restrict__ theta_ps,
    const float* __restrict__ rot_p, float* __restrict__ out)
{
    __shared__ float2 s[1024];
    __shared__ float red[40];
    int b = blockIdx.x;
    int tid = threadIdx.x;

    float a[10];
#pragma unroll
    for (int k = 0; k < 10; ++k) a[k] = ang[b * 10 + k];
    float th[10];
#pragma unroll
    for (int k = 0; k < 10; ++k) th[k] = theta0[k] + a[k];
    th[1] += a[1];
    th[5] -= 0.78539816339745f;   // RX(-pi/4) on wire 5

    float2 v[10][2];
#pragma unroll
    for (int k = 0; k < 10; ++k) {
        float c, sn; sincosf(0.5f * th[k], &sn, &c);
        v[k][0] = make_float2(c, 0.f);
        v[k][1] = make_float2(0.f, -sn);
    }
    { float c, sn; sincosf(0.5f * a[2], &sn, &c);
      float2 v0 = v[2][0], v1 = v[2][1];
      v[2][0] = make_float2(c * v0.x - sn * v1.x, c * v0.y - sn * v1.y);
      v[2][1] = make_float2(sn * v0.x + c * v1.x, sn * v0.y + c * v1.y); }
    { float c, sn; sincosf(0.5f * a[3], &sn, &c);
      v[3][0] = cmul(v[3][0], make_float2(c, -sn));
      v[3][1] = cmul(v[3][1], make_float2(c, sn)); }
    { float2 t = v[4][1]; v[4][1] = make_float2(-t.y, t.x); }
    { const float r = 0.70710678118655f;
      float2 t = v[5][1]; v[5][1] = make_float2(r * (t.x - t.y), r * (t.x + t.y)); }
    { float c, sn; sincosf(0.5f * theta_rz[0], &sn, &c);
      v[6][0] = cmul(v[6][0], make_float2(c, -sn));
      v[6][1] = cmul(v[6][1], make_float2(c, sn)); }
    { float2 p = v[7][0], q = v[7][1];
      v[7][0] = make_float2(0.5f * ((p.x - p.y) + (q.x + q.y)),
                            0.5f * ((p.x + p.y) + (q.y - q.x)));
      v[7][1] = make_float2(0.5f * ((p.x + p.y) + (q.x - q.y)),
                            0.5f * ((p.y - p.x) + (q.x + q.y))); }

    for (int i = tid; i < 1024; i += 256) {
        float2 c = v[0][(i >> 9) & 1];
#pragma unroll
        for (int k = 1; k < 10; ++k)
            c = cmul(c, v[k][(i >> (9 - k)) & 1]);
        s[i] = c;
    }
    __syncthreads();

    for (int i = tid; i < 1024; i += 256)
        if (((i >> 9) & 1) && ((i >> 4) & 1)) { s[i].x = -s[i].x; s[i].y = -s[i].y; }
    __syncthreads();
    { int j = tid;
      int i0 = 512 | ((j >> 4) << 5) | (j & 15);
      int i1 = i0 | 16;
      float2 t0 = s[i0], t1 = s[i1];
      s[i0] = t1; s[i1] = t0; }
    __syncthreads();
    { int j = tid;
      int i0 = 512 | ((j >> 4) << 5) | (j & 15);
      int i1 = i0 | 16;
      float2 t0 = s[i0], t1 = s[i1];
      s[i0] = make_float2(t1.y, -t1.x);
      s[i1] = make_float2(-t0.y, t0.x); }
    __syncthreads();
    { int j = tid;
      int i0 = (j & 1) | (((j >> 1) & 15) << 2) | (((j >> 5) & 7) << 7) | 64;
      int i1 = i0 | 2;
      float2 t0 = s[i0], t1 = s[i1];
      s[i0] = make_float2(t1.y, -t1.x);
      s[i1] = make_float2(-t0.y, t0.x); }
    __syncthreads();
    { int j = tid;
      int i0 = (j & 63) | 128 | (((j >> 6) & 3) << 8);
      int i1 = i0 ^ 0xC0;
      float2 t0 = s[i0], t1 = s[i1];
      s[i0] = t1; s[i1] = t0; }
    __syncthreads();
    if (tid < 128) {
      int j = tid;
      int i0 = (j & 7) | 16 | 32 | (((j >> 3) & 15) << 6);
      int i1 = i0 ^ 0x18;
      float2 t0 = s[i0], t1 = s[i1];
      s[i0] = t1; s[i1] = t0; }
    __syncthreads();
    if (tid < 128) {
      int j = tid;
      int i0 = (j & 1) | 2 | (((j >> 1) & 3) << 2) | 16 | (((j >> 3) & 15) << 5);
      int i1 = i0 | 512;
      float2 t0 = s[i0], t1 = s[i1];
      s[i0] = t1; s[i1] = t0; }
    __syncthreads();
    { float c1, s1; sincosf(theta_ps[0], &s1, &c1);
      float c2, s2; sincosf(a[7], &s2, &c2);
      float2 p1 = make_float2(c1, s1), p2 = make_float2(c2, s2);
      for (int i = tid; i < 1024; i += 256) {
          float2 t = s[i];
          if ((i >> 1) & 1) t = cmul(t, p1);
          if ((i >> 2) & 1) t = cmul(t, p2);
          s[i] = t;
      } }
    __syncthreads();
    apply_rot(s, 5, rot_p[0], rot_p[1], rot_p[2], tid);
    __syncthreads();
    apply_rot(s, 4, a[6], a[7], a[8], tid);
    __syncthreads();

    int wave = tid >> 6;
    for (int k = 0; k < 10; ++k) {
        int p = 9 - k;
        float part = 0.f;
        for (int q = tid; q < 512; q += 256) {
            int i0 = ((q >> p) << (p + 1)) | (q & ((1 << p) - 1));
            int i1 = i0 | (1 << p);
            float2 aa = s[i0], bb = s[i1];
            part += aa.x * bb.y - aa.y * bb.x;
        }
        part *= 2.f;
#pragma unroll
        for (int off = 32; off > 0; off >>= 1)
            part += __shfl_down(part, off, 64);
        if ((tid & 63) == 0) red[k * 4 + wave] = part;
    }
    __syncthreads();
    if (tid == 0) {
        float ev[10];
        float mx = -1e30f;
#pragma unroll
        for (int k = 0; k < 10; ++k) {
            ev[k] = red[k * 4] + red[k * 4 + 1] + red[k * 4 + 2] + red[k * 4 + 3];
            mx = fmaxf(mx, ev[k]);
        }
        float sum = 0.f;
#pragma unroll
        for (int k = 0; k < 10; ++k) sum += expf(ev[k] - mx);
        float lse = mx + logf(sum);
#pragma unroll
        for (int k = 0; k < 10; ++k) out[b * 10 + k] = ev[k] - lse;
    }
}

extern "C" void kernel_launch(void* const* d_in, const int* in_sizes, int n_in,
                              void* d_out, int out_size, void* d_ws, size_t ws_size,
                              hipStream_t stream)
{
    (void)in_sizes; (void)n_in; (void)out_size; (void)ws_size;
    const float* x    = (const float*)d_in[0];
    const float* c1w  = (const float*)d_in[1];
    const float* c1b  = (const float*)d_in[2];
    const float* c2w  = (const float*)d_in[3];
    const float* c2b  = (const float*)d_in[4];
    const float* f1w  = (const float*)d_in[5];
    const float* f1b  = (const float*)d_in[6];
    const float* f2w  = (const float*)d_in[7];
    const float* f2b  = (const float*)d_in[8];
    const float* th0  = (const float*)d_in[9];
    const float* trz  = (const float*)d_in[10];
    const float* tps  = (const float*)d_in[11];
    const float* rotp = (const float*)d_in[12];
    float* out = (float*)d_out;

    char* ws = (char*)d_ws;
    ushort* pooled = (ushort*)(ws);                       // 37,748,736 B
    ushort* wt2    = (ushort*)(ws + 37748736);            //     36,864 B
    ushort* wf1    = (ushort*)(ws + 37785600);            //  2,359,296 B
    float*  part   = (float*)(ws + 40144896);             //  4,194,304 B
    float*  fc1o   = (float*)(ws + 44339200);             //  1,048,576 B
    float*  ang    = (float*)(ws + 45387776);             //     81,920 B

    prep_kernel<<<4680, 256, 0, stream>>>(c2w, f1w, wt2, wf1);
    conv2_banded<<<6144, 384, 0, stream>>>(x, c1w, c1b, wt2, c2b, pooled);
    fc1_mfma<<<dim3(64, 4), 256, 0, stream>>>(pooled, wf1, part);
    fc1_reduce_kernel<<<1024, 256, 0, stream>>>(part, f1b, fc1o);
    fc2_kernel<<<80, 256, 0, stream>>>(fc1o, f2w, f2b, ang);
    quantum_kernel<<<2048, 256, 0, stream>>>(ang, th0, trz, tps, rotp, out);
}

// Round 7
// 231.445 us; speedup vs baseline: 1.0310x; 1.0310x over previous
//
#include <hip/hip_runtime.h>
#include <math.h>

typedef short short8 __attribute__((ext_vector_type(8)));
typedef float f32x4 __attribute__((ext_vector_type(4)));
typedef float f32x16 __attribute__((ext_vector_type(16)));

#define GLB_CP(p) ((const __attribute__((address_space(1))) void*)(p))
#define LDS_CP(p) ((__attribute__((address_space(3))) void*)(p))

__device__ __forceinline__ float2 cmul(float2 a, float2 b) {
    return make_float2(a.x * b.x - a.y * b.y, a.x * b.y + a.y * b.x);
}

__device__ __forceinline__ ushort f2bf(float f) {
    uint u = __float_as_uint(f);
    uint r = (u + 0x7FFFu + ((u >> 16) & 1u)) >> 16;
    return (ushort)r;
}

// ---- prep: conv2 weights -> wt2[tap][icg][oc][ic8] bf16 ; fc1 weights -> bf16 ----
__global__ __launch_bounds__(256) void prep_kernel(
    const float* __restrict__ c2w, const float* __restrict__ f1w,
    ushort* __restrict__ wt2, ushort* __restrict__ wf1)
{
    int i = blockIdx.x * 256 + threadIdx.x;
    if (i < 18432) {
        int icl = i & 7;
        int t = i >> 3;
        int oc = t & 63;
        int t2 = t >> 6;
        int icg = t2 & 3;
        int tap = t2 >> 2;
        int ic = icg * 8 + icl;
        wt2[i] = f2bf(c2w[(oc * 32 + ic) * 9 + tap]);
    } else if (i < 18432 + 1179648) {
        int j = i - 18432;
        wf1[j] = f2bf(f1w[j]);
    }
}

// ---- conv1 + relu -> h1b[b][icg][pix][ic8] bf16 (fully parallel, r3-proven) ----
__global__ __launch_bounds__(256) void conv1_kernel(
    const float* __restrict__ x, const float* __restrict__ w1,
    const float* __restrict__ b1, ushort* __restrict__ h1b)
{
    __shared__ float wl[288];
    __shared__ float bl[32];
    int tid = threadIdx.x;
    for (int e = tid; e < 288; e += 256) wl[e] = w1[e];
    if (tid < 32) bl[tid] = b1[tid];
    __syncthreads();
    int e = blockIdx.x * 256 + tid;          // 2048*676*4 total, exact grid
    int icg = e & 3;
    int t = e >> 2;
    int pix = t % 676;
    int b = t / 676;
    int y = pix / 26, xc = pix % 26;
    const float* xp = x + b * 784 + y * 28 + xc;
    float in9[9];
#pragma unroll
    for (int ky = 0; ky < 3; ++ky)
#pragma unroll
        for (int kx = 0; kx < 3; ++kx) in9[ky * 3 + kx] = xp[ky * 28 + kx];
    short8 outv;
#pragma unroll
    for (int o = 0; o < 8; ++o) {
        int oc = icg * 8 + o;
        float acc = bl[oc];
#pragma unroll
        for (int k = 0; k < 9; ++k) acc = fmaf(in9[k], wl[oc * 9 + k], acc);
        outv[o] = (short)f2bf(fmaxf(acc, 0.f));
    }
    *(short8*)&h1b[((b * 4 + icg) * 676 + pix) * 8] = outv;
}

// ---- conv2 banded MFMA: async-staged LDS, pure MFMA phase, shfl-maxpool ----
// block = (image, band of 8 conv rows); 384 thr = 6 waves, wave = 8x4 px region.
// LDS: input 17,408 B + weights 36,864 B + bias 256 B = 54,528 B -> 2 blocks/CU.
__global__ __launch_bounds__(384, 3) void conv2_banded(
    const ushort* __restrict__ h1b, const ushort* __restrict__ wt2,
    const float* __restrict__ c2b, ushort* __restrict__ pooled)
{
    __shared__ __attribute__((aligned(16))) ushort in_lds[8704];   // [icg 4][260][ic8] + pad
    __shared__ __attribute__((aligned(16))) ushort wt_lds[18432];  // [tap 9][icg 4][oc 64][ic8]
    __shared__ float b2s[64];
    int bx = blockIdx.x;
    int b = bx / 3;
    int band = bx % 3;
    int r0 = band * 8;
    int tid = threadIdx.x;
    int wave = tid >> 6;
    int lane = tid & 63;

    // async stage: 17 input chunks (1040 short8 + pad) + 36 weight chunks (2304 short8)
    for (int c = wave; c < 53; c += 6) {
        if (c < 17) {
            int e = c * 64 + lane;
            if (e > 1039) e = 1039;                    // clamp; pad slots get dup data
            int icg = e / 260;
            int rem = e - icg * 260;                   // row*26+col, band-local
            const ushort* src = h1b + ((size_t)(b * 4 + icg) * 676 + r0 * 26 + rem) * 8;
            __builtin_amdgcn_global_load_lds(GLB_CP(src), LDS_CP(in_lds + c * 512), 16, 0, 0);
        } else {
            int e = (c - 17) * 64 + lane;              // < 2304 exact
            const ushort* src = wt2 + e * 8;
            __builtin_amdgcn_global_load_lds(GLB_CP(src), LDS_CP(wt_lds + (c - 17) * 512), 16, 0, 0);
        }
    }
    if (tid < 16) ((uint4*)b2s)[tid] = ((const uint4*)c2b)[tid];
    __syncthreads();

    int lo = lane & 31;
    int hi = lane >> 5;
    int rx = wave % 3, ry = wave / 3;        // region: 8 wide x 4 tall
    int xcoord = rx * 8 + (lo & 7);
    int ycoord = ry * 4 + (lo >> 3);         // band-local conv row 0..7
    int pbase = ycoord * 26 + xcoord;

    f32x16 acc0 = (f32x16)0.f, acc1 = (f32x16)0.f;

#pragma unroll
    for (int tap = 0; tap < 9; ++tap) {
        int off = (tap / 3) * 26 + (tap % 3);
#pragma unroll
        for (int ks = 0; ks < 2; ++ks) {
            short8 bf = *(const short8*)&in_lds[((ks * 2 + hi) * 260 + pbase + off) * 8];
            short8 a0 = *(const short8*)&wt_lds[((tap * 4 + ks * 2 + hi) * 64 + lo) * 8];
            short8 a1 = *(const short8*)&wt_lds[((tap * 4 + ks * 2 + hi) * 64 + 32 + lo) * 8];
            acc0 = __builtin_amdgcn_mfma_f32_32x32x16_bf16(a0, bf, acc0, 0, 0, 0);
            acc1 = __builtin_amdgcn_mfma_f32_32x32x16_bf16(a1, bf, acc1, 0, 0, 0);
        }
    }

    // epilogue: bias + relu + 2x2 maxpool via shfl, packed bf16-pair stores (r5-proven)
    ushort* pout = pooled + (size_t)b * 9216;
    int prow = band * 4 + ry * 2 + (lo >> 4);
    int pcol = rx * 4 + ((lo >> 1) & 3);
    bool st = (lo & 0xB) == 0;               // lo in {0,4,16,20}
#pragma unroll
    for (int mt = 0; mt < 2; ++mt) {
#pragma unroll
        for (int r = 0; r < 16; ++r) {
            int oc = mt * 32 + (r & 3) + 8 * (r >> 2) + 4 * hi;
            float v = (mt ? acc1[r] : acc0[r]) + b2s[oc];
            v = fmaxf(v, 0.f);
            float m = fmaxf(v, __shfl_xor(v, 1, 64));
            m = fmaxf(m, __shfl_xor(m, 8, 64));
            float mp = __shfl_xor(m, 2, 64);
            if (st) {
                uint pk = (uint)f2bf(m) | ((uint)f2bf(mp) << 16);
                *(uint*)&pout[oc * 144 + prow * 12 + pcol] = pk;
            }
        }
    }
}

// ---- fc1 MFMA: pooled[2048,9216]bf16 x wf1[128,9216]bf16^T, 4-way K-split ----
__global__ __launch_bounds__(256) void fc1_mfma(
    const ushort* __restrict__ pooled, const ushort* __restrict__ wf1,
    float* __restrict__ part)
{
    int bx = blockIdx.x, by = blockIdx.y;
    int tid = threadIdx.x;
    int wid = tid >> 6, lane = tid & 63;
    int lo = lane & 15, hi = lane >> 4;
    int m0 = bx * 32;
    int kb = by * 2304;

    f32x4 acc[2][2];
#pragma unroll
    for (int mt = 0; mt < 2; ++mt)
#pragma unroll
        for (int j = 0; j < 2; ++j) acc[mt][j] = (f32x4)0.f;

    const ushort* arow0 = pooled + (size_t)(m0 + lo) * 9216 + kb + hi * 8;
    const ushort* arow1 = arow0 + 16 * 9216;
    const ushort* brow0 = wf1 + (size_t)(wid * 32 + lo) * 9216 + kb + hi * 8;
    const ushort* brow1 = brow0 + 16 * 9216;

    for (int kt = 0; kt < 72; ++kt) {
        short8 a0 = *(const short8*)(arow0 + kt * 32);
        short8 a1 = *(const short8*)(arow1 + kt * 32);
        short8 b0 = *(const short8*)(brow0 + kt * 32);
        short8 b1 = *(const short8*)(brow1 + kt * 32);
        acc[0][0] = __builtin_amdgcn_mfma_f32_16x16x32_bf16(a0, b0, acc[0][0], 0, 0, 0);
        acc[1][0] = __builtin_amdgcn_mfma_f32_16x16x32_bf16(a1, b0, acc[1][0], 0, 0, 0);
        acc[0][1] = __builtin_amdgcn_mfma_f32_16x16x32_bf16(a0, b1, acc[0][1], 0, 0, 0);
        acc[1][1] = __builtin_amdgcn_mfma_f32_16x16x32_bf16(a1, b1, acc[1][1], 0, 0, 0);
    }
    float* pp = part + (size_t)by * 262144;
#pragma unroll
    for (int mt = 0; mt < 2; ++mt)
#pragma unroll
        for (int j = 0; j < 2; ++j)
#pragma unroll
            for (int r = 0; r < 4; ++r)
                pp[(m0 + mt * 16 + hi * 4 + r) * 128 + wid * 32 + j * 16 + lo] = acc[mt][j][r];
}

__global__ __launch_bounds__(256) void fc1_reduce_kernel(
    const float* __restrict__ part, const float* __restrict__ bias,
    float* __restrict__ outp)
{
    int idx = blockIdx.x * 256 + threadIdx.x;   // < 262144
    float s = 0.f;
#pragma unroll
    for (int ks = 0; ks < 4; ++ks) s += part[ks * 262144 + idx];
    outp[idx] = fmaxf(s + bias[idx & 127], 0.f);
}

// ---- fc2 + sigmoid*2pi -> angles[2048,10] ----
__global__ __launch_bounds__(256) void fc2_kernel(
    const float* __restrict__ h, const float* __restrict__ w,
    const float* __restrict__ bias, float* __restrict__ ang)
{
    int idx = blockIdx.x * 256 + threadIdx.x;
    if (idx >= 20480) return;
    int b = idx / 10, n = idx % 10;
    const float* hp = h + b * 128;
    const float* wp = w + n * 128;
    float s = bias[n];
    for (int k = 0; k < 128; ++k) s = fmaf(hp[k], wp[k], s);
    ang[idx] = 6.28318530718f / (1.f + expf(-s));
}

// ---------------- quantum circuit + <Y_k> + log_softmax ----------------
__device__ __forceinline__ void apply_rot(float2* s, int p, float phi, float th,
                                          float om, int tid)
{
    float c, sn; sincosf(0.5f * th, &sn, &c);
    float A = 0.5f * (phi + om), Bv = 0.5f * (phi - om);
    float cA, sA; sincosf(A, &sA, &cA);
    float cB, sB; sincosf(Bv, &sB, &cB);
    float2 m00 = make_float2(cA * c, -sA * c);
    float2 m01 = make_float2(-cB * sn, -sB * sn);
    float2 m10 = make_float2(cB * sn, -sB * sn);
    float2 m11 = make_float2(cA * c, sA * c);
    for (int q = tid; q < 512; q += 256) {
        int i0 = ((q >> p) << (p + 1)) | (q & ((1 << p) - 1));
        int i1 = i0 | (1 << p);
        float2 aa = s[i0], bb = s[i1];
        s[i0] = make_float2(m00.x * aa.x - m00.y * aa.y + m01.x * bb.x - m01.y * bb.y,
                            m00.x * aa.y + m00.y * aa.x + m01.x * bb.y + m01.y * bb.x);
        s[i1] = make_float2(m10.x * aa.x - m10.y * aa.y + m11.x * bb.x - m11.y * bb.y,
                            m10.x * aa.y + m10.y * aa.x + m11.x * bb.y + m11.y * bb.x);
    }
}

__global__ __launch_bounds__(256) void quantum_kernel(
    const float* __restrict__ ang, const float* __restrict__ theta0,
    const float* __restrict__ theta_rz, const float* __restrict__ theta_ps,
    const float* __restrict__ rot_p, float* __restrict__ out)
{
    __shared__ float2 s[1024];
    __shared__ float red[40];
    int b = blockIdx.x;
    int tid = threadIdx.x;

    float a[10];
#pragma unroll
    for (int k = 0; k < 10; ++k) a[k] = ang[b * 10 + k];
    float th[10];
#pragma unroll
    for (int k = 0; k < 10; ++k) th[k] = theta0[k] + a[k];
    th[1] += a[1];
    th[5] -= 0.78539816339745f;   // RX(-pi/4) on wire 5

    float2 v[10][2];
#pragma unroll
    for (int k = 0; k < 10; ++k) {
        float c, sn; sincosf(0.5f * th[k], &sn, &c);
        v[k][0] = make_float2(c, 0.f);
        v[k][1] = make_float2(0.f, -sn);
    }
    { float c, sn; sincosf(0.5f * a[2], &sn, &c);
      float2 v0 = v[2][0], v1 = v[2][1];
      v[2][0] = make_float2(c * v0.x - sn * v1.x, c * v0.y - sn * v1.y);
      v[2][1] = make_float2(sn * v0.x + c * v1.x, sn * v0.y + c * v1.y); }
    { float c, sn; sincosf(0.5f * a[3], &sn, &c);
      v[3][0] = cmul(v[3][0], make_float2(c, -sn));
      v[3][1] = cmul(v[3][1], make_float2(c, sn)); }
    { float2 t = v[4][1]; v[4][1] = make_float2(-t.y, t.x); }
    { const float r = 0.70710678118655f;
      float2 t = v[5][1]; v[5][1] = make_float2(r * (t.x - t.y), r * (t.x + t.y)); }
    { float c, sn; sincosf(0.5f * theta_rz[0], &sn, &c);
      v[6][0] = cmul(v[6][0], make_float2(c, -sn));
      v[6][1] = cmul(v[6][1], make_float2(c, sn)); }
    { float2 p = v[7][0], q = v[7][1];
      v[7][0] = make_float2(0.5f * ((p.x - p.y) + (q.x + q.y)),
                            0.5f * ((p.x + p.y) + (q.y - q.x)));
      v[7][1] = make_float2(0.5f * ((p.x + p.y) + (q.x - q.y)),
                            0.5f * ((p.y - p.x) + (q.x + q.y))); }

    for (int i = tid; i < 1024; i += 256) {
        float2 c = v[0][(i >> 9) & 1];
#pragma unroll
        for (int k = 1; k < 10; ++k)
            c = cmul(c, v[k][(i >> (9 - k)) & 1]);
        s[i] = c;
    }
    __syncthreads();

    for (int i = tid; i < 1024; i += 256)
        if (((i >> 9) & 1) && ((i >> 4) & 1)) { s[i].x = -s[i].x; s[i].y = -s[i].y; }
    __syncthreads();
    { int j = tid;
      int i0 = 512 | ((j >> 4) << 5) | (j & 15);
      int i1 = i0 | 16;
      float2 t0 = s[i0], t1 = s[i1];
      s[i0] = t1; s[i1] = t0; }
    __syncthreads();
    { int j = tid;
      int i0 = 512 | ((j >> 4) << 5) | (j & 15);
      int i1 = i0 | 16;
      float2 t0 = s[i0], t1 = s[i1];
      s[i0] = make_float2(t1.y, -t1.x);
      s[i1] = make_float2(-t0.y, t0.x); }
    __syncthreads();
    { int j = tid;
      int i0 = (j & 1) | (((j >> 1) & 15) << 2) | (((j >> 5) & 7) << 7) | 64;
      int i1 = i0 | 2;
      float2 t0 = s[i0], t1 = s[i1];
      s[i0] = make_float2(t1.y, -t1.x);
      s[i1] = make_float2(-t0.y, t0.x); }
    __syncthreads();
    { int j = tid;
      int i0 = (j & 63) | 128 | (((j >> 6) & 3) << 8);
      int i1 = i0 ^ 0xC0;
      float2 t0 = s[i0], t1 = s[i1];
      s[i0] = t1; s[i1] = t0; }
    __syncthreads();
    if (tid < 128) {
      int j = tid;
      int i0 = (j & 7) | 16 | 32 | (((j >> 3) & 15) << 6);
      int i1 = i0 ^ 0x18;
      float2 t0 = s[i0], t1 = s[i1];
      s[i0] = t1; s[i1] = t0; }
    __syncthreads();
    if (tid < 128) {
      int j = tid;
      int i0 = (j & 1) | 2 | (((j >> 1) & 3) << 2) | 16 | (((j >> 3) & 15) << 5);
      int i1 = i0 | 512;
      float2 t0 = s[i0], t1 = s[i1];
      s[i0] = t1; s[i1] = t0; }
    __syncthreads();
    { float c1, s1; sincosf(theta_ps[0], &s1, &c1);
      float c2, s2; sincosf(a[7], &s2, &c2);
      float2 p1 = make_float2(c1, s1), p2 = make_float2(c2, s2);
      for (int i = tid; i < 1024; i += 256) {
          float2 t = s[i];
          if ((i >> 1) & 1) t = cmul(t, p1);
          if ((i >> 2) & 1) t = cmul(t, p2);
          s[i] = t;
      } }
    __syncthreads();
    apply_rot(s, 5, rot_p[0], rot_p[1], rot_p[2], tid);
    __syncthreads();
    apply_rot(s, 4, a[6], a[7], a[8], tid);
    __syncthreads();

    int wave = tid >> 6;
    for (int k = 0; k < 10; ++k) {
        int p = 9 - k;
        float part = 0.f;
        for (int q = tid; q < 512; q += 256) {
            int i0 = ((q >> p) << (p + 1)) | (q & ((1 << p) - 1));
            int i1 = i0 | (1 << p);
            float2 aa = s[i0], bb = s[i1];
            part += aa.x * bb.y - aa.y * bb.x;
        }
        part *= 2.f;
#pragma unroll
        for (int off = 32; off > 0; off >>= 1)
            part += __shfl_down(part, off, 64);
        if ((tid & 63) == 0) red[k * 4 + wave] = part;
    }
    __syncthreads();
    if (tid == 0) {
        float ev[10];
        float mx = -1e30f;
#pragma unroll
        for (int k = 0; k < 10; ++k) {
            ev[k] = red[k * 4] + red[k * 4 + 1] + red[k * 4 + 2] + red[k * 4 + 3];
            mx = fmaxf(mx, ev[k]);
        }
        float sum = 0.f;
#pragma unroll
        for (int k = 0; k < 10; ++k) sum += expf(ev[k] - mx);
        float lse = mx + logf(sum);
#pragma unroll
        for (int k = 0; k < 10; ++k) out[b * 10 + k] = ev[k] - lse;
    }
}

extern "C" void kernel_launch(void* const* d_in, const int* in_sizes, int n_in,
                              void* d_out, int out_size, void* d_ws, size_t ws_size,
                              hipStream_t stream)
{
    (void)in_sizes; (void)n_in; (void)out_size; (void)ws_size;
    const float* x    = (const float*)d_in[0];
    const float* c1w  = (const float*)d_in[1];
    const float* c1b  = (const float*)d_in[2];
    const float* c2w  = (const float*)d_in[3];
    const float* c2b  = (const float*)d_in[4];
    const float* f1w  = (const float*)d_in[5];
    const float* f1b  = (const float*)d_in[6];
    const float* f2w  = (const float*)d_in[7];
    const float* f2b  = (const float*)d_in[8];
    const float* th0  = (const float*)d_in[9];
    const float* trz  = (const float*)d_in[10];
    const float* tps  = (const float*)d_in[11];
    const float* rotp = (const float*)d_in[12];
    float* out = (float*)d_out;

    char* ws = (char*)d_ws;
    ushort* h1b    = (ushort*)(ws);                       // 88,604,672 B
    ushort* pooled = (ushort*)(ws + 88604672);            // 37,748,736 B
    ushort* wt2    = (ushort*)(ws + 126353408);           //     36,864 B
    ushort* wf1    = (ushort*)(ws + 126390272);           //  2,359,296 B
    float*  part   = (float*)(ws + 128749568);            //  4,194,304 B
    float*  fc1o   = (float*)(ws + 132943872);            //  1,048,576 B
    float*  ang    = (float*)(ws + 133992448);            //     81,920 B

    prep_kernel<<<4680, 256, 0, stream>>>(c2w, f1w, wt2, wf1);
    conv1_kernel<<<21632, 256, 0, stream>>>(x, c1w, c1b, h1b);
    conv2_banded<<<6144, 384, 0, stream>>>(h1b, wt2, c2b, pooled);
    fc1_mfma<<<dim3(64, 4), 256, 0, stream>>>(pooled, wf1, part);
    fc1_reduce_kernel<<<1024, 256, 0, stream>>>(part, f1b, fc1o);
    fc2_kernel<<<80, 256, 0, stream>>>(fc1o, f2w, f2b, ang);
    quantum_kernel<<<2048, 256, 0, stream>>>(ang, th0, trz, tps, rotp, out);
}

// Round 8
// 183.277 us; speedup vs baseline: 1.3019x; 1.2628x over previous
//
#include <hip/hip_runtime.h>
#include <math.h>

typedef short short8 __attribute__((ext_vector_type(8)));
typedef float f32x4 __attribute__((ext_vector_type(4)));
typedef float f32x16 __attribute__((ext_vector_type(16)));

#define GLB_CP(p) ((const __attribute__((address_space(1))) void*)(p))
#define LDS_CP(p) ((__attribute__((address_space(3))) void*)(p))

__device__ __forceinline__ float2 cmul(float2 a, float2 b) {
    return make_float2(a.x * b.x - a.y * b.y, a.x * b.y + a.y * b.x);
}

__device__ __forceinline__ ushort f2bf(float f) {
    uint u = __float_as_uint(f);
    uint r = (u + 0x7FFFu + ((u >> 16) & 1u)) >> 16;
    return (ushort)r;
}

// ---- prep: conv2 weights -> wt2[tap][icg][oc][ic8] bf16 ; fc1 weights -> bf16 ----
__global__ __launch_bounds__(256) void prep_kernel(
    const float* __restrict__ c2w, const float* __restrict__ f1w,
    ushort* __restrict__ wt2, ushort* __restrict__ wf1)
{
    int i = blockIdx.x * 256 + threadIdx.x;
    if (i < 18432) {
        int icl = i & 7;
        int t = i >> 3;
        int oc = t & 63;
        int t2 = t >> 6;
        int icg = t2 & 3;
        int tap = t2 >> 2;
        int ic = icg * 8 + icl;
        wt2[i] = f2bf(c2w[(oc * 32 + ic) * 9 + tap]);
    } else if (i < 18432 + 1179648) {
        int j = i - 18432;
        wf1[j] = f2bf(f1w[j]);
    }
}

// ---- conv1 + relu -> h1b[b][icg][pix][ic8] bf16 (fully parallel, r3-proven) ----
__global__ __launch_bounds__(256) void conv1_kernel(
    const float* __restrict__ x, const float* __restrict__ w1,
    const float* __restrict__ b1, ushort* __restrict__ h1b)
{
    __shared__ float wl[288];
    __shared__ float bl[32];
    int tid = threadIdx.x;
    for (int e = tid; e < 288; e += 256) wl[e] = w1[e];
    if (tid < 32) bl[tid] = b1[tid];
    __syncthreads();
    int e = blockIdx.x * 256 + tid;          // 2048*676*4 total, exact grid
    int icg = e & 3;
    int t = e >> 2;
    int pix = t % 676;
    int b = t / 676;
    int y = pix / 26, xc = pix % 26;
    const float* xp = x + b * 784 + y * 28 + xc;
    float in9[9];
#pragma unroll
    for (int ky = 0; ky < 3; ++ky)
#pragma unroll
        for (int kx = 0; kx < 3; ++kx) in9[ky * 3 + kx] = xp[ky * 28 + kx];
    short8 outv;
#pragma unroll
    for (int o = 0; o < 8; ++o) {
        int oc = icg * 8 + o;
        float acc = bl[oc];
#pragma unroll
        for (int k = 0; k < 9; ++k) acc = fmaf(in9[k], wl[oc * 9 + k], acc);
        outv[o] = (short)f2bf(fmaxf(acc, 0.f));
    }
    *(short8*)&h1b[((b * 4 + icg) * 676 + pix) * 8] = outv;
}

// ---- conv2 banded MFMA: swapped operands -> register-only 2x2 maxpool ----
// block = (image, band of 8 conv rows); 384 thr = 6 waves, wave = 8x4 px region.
// mfma(pixels, weights): C row = pixel ((r&3)+4hi, r>>2), col = oc = lane&31.
// LDS: input 17,408 B + weights taps 0-7 32,768 B = 50,176 B -> 3 blocks/CU.
__global__ __launch_bounds__(384, 4) void conv2_banded(
    const ushort* __restrict__ h1b, const ushort* __restrict__ wt2,
    const float* __restrict__ c2b, ushort* __restrict__ pooled)
{
    __shared__ __attribute__((aligned(16))) ushort in_lds[8704];   // [icg 4][260][ic8] + pad
    __shared__ __attribute__((aligned(16))) ushort wt_lds[16384];  // [tap 8][icg 4][oc 64][ic8]
    int bx = blockIdx.x;
    int b = bx / 3;
    int band = bx % 3;
    int r0 = band * 8;
    int tid = threadIdx.x;
    int wave = tid >> 6;
    int lane = tid & 63;
    int lo = lane & 31;
    int hi = lane >> 5;

    // async stage: 17 input chunks + 32 weight chunks (taps 0-7)
    for (int c = wave; c < 49; c += 6) {
        if (c < 17) {
            int e = c * 64 + lane;
            if (e > 1039) e = 1039;                    // clamp; pad slots get dup data
            int icg = e / 260;
            int rem = e - icg * 260;                   // row*26+col, band-local
            const ushort* src = h1b + ((size_t)(b * 4 + icg) * 676 + r0 * 26 + rem) * 8;
            __builtin_amdgcn_global_load_lds(GLB_CP(src), LDS_CP(in_lds + c * 512), 16, 0, 0);
        } else {
            int e = (c - 17) * 64 + lane;              // < 2048 exact
            const ushort* src = wt2 + e * 8;
            __builtin_amdgcn_global_load_lds(GLB_CP(src), LDS_CP(wt_lds + (c - 17) * 512), 16, 0, 0);
        }
    }

    // tap-8 weight fragments direct from global (L2-hot), issued early
    short8 w8[2][2];
#pragma unroll
    for (int ks = 0; ks < 2; ++ks)
#pragma unroll
        for (int m = 0; m < 2; ++m)
            w8[ks][m] = *(const short8*)(wt2 + (size_t)((32 + ks * 2 + hi) * 64 + m * 32 + lo) * 8);
    float bias0 = c2b[lo];
    float bias1 = c2b[lo + 32];
    __syncthreads();

    int rx = wave % 3, ry = wave / 3;        // region: 8 wide x 4 tall
    int xcoord = rx * 8 + (lo & 7);
    int ycoord = ry * 4 + (lo >> 3);         // band-local conv row 0..7
    int pbase = ycoord * 26 + xcoord;

    f32x16 acc0 = (f32x16)0.f, acc1 = (f32x16)0.f;

#pragma unroll
    for (int tap = 0; tap < 8; ++tap) {
        int off = (tap / 3) * 26 + (tap % 3);
#pragma unroll
        for (int ks = 0; ks < 2; ++ks) {
            short8 bf = *(const short8*)&in_lds[((ks * 2 + hi) * 260 + pbase + off) * 8];
            short8 a0 = *(const short8*)&wt_lds[((tap * 4 + ks * 2 + hi) * 64 + lo) * 8];
            short8 a1 = *(const short8*)&wt_lds[((tap * 4 + ks * 2 + hi) * 64 + 32 + lo) * 8];
            acc0 = __builtin_amdgcn_mfma_f32_32x32x16_bf16(bf, a0, acc0, 0, 0, 0);
            acc1 = __builtin_amdgcn_mfma_f32_32x32x16_bf16(bf, a1, acc1, 0, 0, 0);
        }
    }
    { // tap 8 from prefetched registers
        int off = 2 * 26 + 2;
#pragma unroll
        for (int ks = 0; ks < 2; ++ks) {
            short8 bf = *(const short8*)&in_lds[((ks * 2 + hi) * 260 + pbase + off) * 8];
            acc0 = __builtin_amdgcn_mfma_f32_32x32x16_bf16(bf, w8[ks][0], acc0, 0, 0, 0);
            acc1 = __builtin_amdgcn_mfma_f32_32x32x16_bf16(bf, w8[ks][1], acc1, 0, 0, 0);
        }
    }

    // register-only epilogue: 2x2 pool quadruple = regs {b,b+1,b+4,b+5}, b in {0,2,8,10}
    ushort* pout = pooled + (size_t)b * 9216;
    int pcolb = rx * 4 + 2 * hi;             // even; pack (p=0,p=1) into one uint
#pragma unroll
    for (int q = 0; q < 2; ++q) {
        int prow = band * 4 + ry * 2 + q;
        int base = 8 * q;
        float m00 = fmaxf(fmaxf(acc0[base], acc0[base + 1]), fmaxf(acc0[base + 4], acc0[base + 5]));
        float m01 = fmaxf(fmaxf(acc0[base + 2], acc0[base + 3]), fmaxf(acc0[base + 6], acc0[base + 7]));
        uint pk0 = (uint)f2bf(fmaxf(m00 + bias0, 0.f)) | ((uint)f2bf(fmaxf(m01 + bias0, 0.f)) << 16);
        *(uint*)&pout[lo * 144 + prow * 12 + pcolb] = pk0;
        float m10 = fmaxf(fmaxf(acc1[base], acc1[base + 1]), fmaxf(acc1[base + 4], acc1[base + 5]));
        float m11 = fmaxf(fmaxf(acc1[base + 2], acc1[base + 3]), fmaxf(acc1[base + 6], acc1[base + 7]));
        uint pk1 = (uint)f2bf(fmaxf(m10 + bias1, 0.f)) | ((uint)f2bf(fmaxf(m11 + bias1, 0.f)) << 16);
        *(uint*)&pout[(lo + 32) * 144 + prow * 12 + pcolb] = pk1;
    }
}

// ---- fc1 MFMA: pooled[2048,9216]bf16 x wf1[128,9216]bf16^T, 4-way K-split ----
__global__ __launch_bounds__(256) void fc1_mfma(
    const ushort* __restrict__ pooled, const ushort* __restrict__ wf1,
    float* __restrict__ part)
{
    int bx = blockIdx.x, by = blockIdx.y;
    int tid = threadIdx.x;
    int wid = tid >> 6, lane = tid & 63;
    int lo = lane & 15, hi = lane >> 4;
    int m0 = bx * 32;
    int kb = by * 2304;

    f32x4 acc[2][2];
#pragma unroll
    for (int mt = 0; mt < 2; ++mt)
#pragma unroll
        for (int j = 0; j < 2; ++j) acc[mt][j] = (f32x4)0.f;

    const ushort* arow0 = pooled + (size_t)(m0 + lo) * 9216 + kb + hi * 8;
    const ushort* arow1 = arow0 + 16 * 9216;
    const ushort* brow0 = wf1 + (size_t)(wid * 32 + lo) * 9216 + kb + hi * 8;
    const ushort* brow1 = brow0 + 16 * 9216;

    for (int kt = 0; kt < 72; ++kt) {
        short8 a0 = *(const short8*)(arow0 + kt * 32);
        short8 a1 = *(const short8*)(arow1 + kt * 32);
        short8 b0 = *(const short8*)(brow0 + kt * 32);
        short8 b1 = *(const short8*)(brow1 + kt * 32);
        acc[0][0] = __builtin_amdgcn_mfma_f32_16x16x32_bf16(a0, b0, acc[0][0], 0, 0, 0);
        acc[1][0] = __builtin_amdgcn_mfma_f32_16x16x32_bf16(a1, b0, acc[1][0], 0, 0, 0);
        acc[0][1] = __builtin_amdgcn_mfma_f32_16x16x32_bf16(a0, b1, acc[0][1], 0, 0, 0);
        acc[1][1] = __builtin_amdgcn_mfma_f32_16x16x32_bf16(a1, b1, acc[1][1], 0, 0, 0);
    }
    float* pp = part + (size_t)by * 262144;
#pragma unroll
    for (int mt = 0; mt < 2; ++mt)
#pragma unroll
        for (int j = 0; j < 2; ++j)
#pragma unroll
            for (int r = 0; r < 4; ++r)
                pp[(m0 + mt * 16 + hi * 4 + r) * 128 + wid * 32 + j * 16 + lo] = acc[mt][j][r];
}

__global__ __launch_bounds__(256) void fc1_reduce_kernel(
    const float* __restrict__ part, const float* __restrict__ bias,
    float* __restrict__ outp)
{
    int idx = blockIdx.x * 256 + threadIdx.x;   // < 262144
    float s = 0.f;
#pragma unroll
    for (int ks = 0; ks < 4; ++ks) s += part[ks * 262144 + idx];
    outp[idx] = fmaxf(s + bias[idx & 127], 0.f);
}

// ---- fc2 + sigmoid*2pi -> angles[2048,10] ----
__global__ __launch_bounds__(256) void fc2_kernel(
    const float* __restrict__ h, const float* __restrict__ w,
    const float* __restrict__ bias, float* __restrict__ ang)
{
    int idx = blockIdx.x * 256 + threadIdx.x;
    if (idx >= 20480) return;
    int b = idx / 10, n = idx % 10;
    const float* hp = h + b * 128;
    const float* wp = w + n * 128;
    float s = bias[n];
    for (int k = 0; k < 128; ++k) s = fmaf(hp[k], wp[k], s);
    ang[idx] = 6.28318530718f / (1.f + expf(-s));
}

// ---------------- quantum circuit + <Y_k> + log_softmax ----------------
__device__ __forceinline__ void apply_rot(float2* s, int p, float phi, float th,
                                          float om, int tid)
{
    float c, sn; sincosf(0.5f * th, &sn, &c);
    float A = 0.5f * (phi + om), Bv = 0.5f * (phi - om);
    float cA, sA; sincosf(A, &sA, &cA);
    float cB, sB; sincosf(Bv, &sB, &cB);
    float2 m00 = make_float2(cA * c, -sA * c);
    float2 m01 = make_float2(-cB * sn, -sB * sn);
    float2 m10 = make_float2(cB * sn, -sB * sn);
    float2 m11 = make_float2(cA * c, sA * c);
    for (int q = tid; q < 512; q += 256) {
        int i0 = ((q >> p) << (p + 1)) | (q & ((1 << p) - 1));
        int i1 = i0 | (1 << p);
        float2 aa = s[i0], bb = s[i1];
        s[i0] = make_float2(m00.x * aa.x - m00.y * aa.y + m01.x * bb.x - m01.y * bb.y,
                            m00.x * aa.y + m00.y * aa.x + m01.x * bb.y + m01.y * bb.x);
        s[i1] = make_float2(m10.x * aa.x - m10.y * aa.y + m11.x * bb.x - m11.y * bb.y,
                            m10.x * aa.y + m10.y * aa.x + m11.x * bb.y + m11.y * bb.x);
    }
}

__global__ __launch_bounds__(256) void quantum_kernel(
    const float* __restrict__ ang, const float* __restrict__ theta0,
    const float* __restrict__ theta_rz, const float* __restrict__ theta_ps,
    const float* __restrict__ rot_p, float* __restrict__ out)
{
    __shared__ float2 s[1024];
    __shared__ float red[40];
    int b = blockIdx.x;
    int tid = threadIdx.x;

    float a[10];
#pragma unroll
    for (int k = 0; k < 10; ++k) a[k] = ang[b * 10 + k];
    float th[10];
#pragma unroll
    for (int k = 0; k < 10; ++k) th[k] = theta0[k] + a[k];
    th[1] += a[1];
    th[5] -= 0.78539816339745f;   // RX(-pi/4) on wire 5

    float2 v[10][2];
#pragma unroll
    for (int k = 0; k < 10; ++k) {
        float c, sn; sincosf(0.5f * th[k], &sn, &c);
        v[k][0] = make_float2(c, 0.f);
        v[k][1] = make_float2(0.f, -sn);
    }
    { float c, sn; sincosf(0.5f * a[2], &sn, &c);
      float2 v0 = v[2][0], v1 = v[2][1];
      v[2][0] = make_float2(c * v0.x - sn * v1.x, c * v0.y - sn * v1.y);
      v[2][1] = make_float2(sn * v0.x + c * v1.x, sn * v0.y + c * v1.y); }
    { float c, sn; sincosf(0.5f * a[3], &sn, &c);
      v[3][0] = cmul(v[3][0], make_float2(c, -sn));
      v[3][1] = cmul(v[3][1], make_float2(c, sn)); }
    { float2 t = v[4][1]; v[4][1] = make_float2(-t.y, t.x); }
    { const float r = 0.70710678118655f;
      float2 t = v[5][1]; v[5][1] = make_float2(r * (t.x - t.y), r * (t.x + t.y)); }
    { float c, sn; sincosf(0.5f * theta_rz[0], &sn, &c);
      v[6][0] = cmul(v[6][0], make_float2(c, -sn));
      v[6][1] = cmul(v[6][1], make_float2(c, sn)); }
    { float2 p = v[7][0], q = v[7][1];
      v[7][0] = make_float2(0.5f * ((p.x - p.y) + (q.x + q.y)),
                            0.5f * ((p.x + p.y) + (q.y - q.x)));
      v[7][1] = make_float2(0.5f * ((p.x + p.y) + (q.x - q.y)),
                            0.5f * ((p.y - p.x) + (q.x + q.y))); }

    for (int i = tid; i < 1024; i += 256) {
        float2 c = v[0][(i >> 9) & 1];
#pragma unroll
        for (int k = 1; k < 10; ++k)
            c = cmul(c, v[k][(i >> (9 - k)) & 1]);
        s[i] = c;
    }
    __syncthreads();

    for (int i = tid; i < 1024; i += 256)
        if (((i >> 9) & 1) && ((i >> 4) & 1)) { s[i].x = -s[i].x; s[i].y = -s[i].y; }
    __syncthreads();
    { int j = tid;
      int i0 = 512 | ((j >> 4) << 5) | (j & 15);
      int i1 = i0 | 16;
      float2 t0 = s[i0], t1 = s[i1];
      s[i0] = t1; s[i1] = t0; }
    __syncthreads();
    { int j = tid;
      int i0 = 512 | ((j >> 4) << 5) | (j & 15);
      int i1 = i0 | 16;
      float2 t0 = s[i0], t1 = s[i1];
      s[i0] = make_float2(t1.y, -t1.x);
      s[i1] = make_float2(-t0.y, t0.x); }
    __syncthreads();
    { int j = tid;
      int i0 = (j & 1) | (((j >> 1) & 15) << 2) | (((j >> 5) & 7) << 7) | 64;
      int i1 = i0 | 2;
      float2 t0 = s[i0], t1 = s[i1];
      s[i0] = make_float2(t1.y, -t1.x);
      s[i1] = make_float2(-t0.y, t0.x); }
    __syncthreads();
    { int j = tid;
      int i0 = (j & 63) | 128 | (((j >> 6) & 3) << 8);
      int i1 = i0 ^ 0xC0;
      float2 t0 = s[i0], t1 = s[i1];
      s[i0] = t1; s[i1] = t0; }
    __syncthreads();
    if (tid < 128) {
      int j = tid;
      int i0 = (j & 7) | 16 | 32 | (((j >> 3) & 15) << 6);
      int i1 = i0 ^ 0x18;
      float2 t0 = s[i0], t1 = s[i1];
      s[i0] = t1; s[i1] = t0; }
    __syncthreads();
    if (tid < 128) {
      int j = tid;
      int i0 = (j & 1) | 2 | (((j >> 1) & 3) << 2) | 16 | (((j >> 3) & 15) << 5);
      int i1 = i0 | 512;
      float2 t0 = s[i0], t1 = s[i1];
      s[i0] = t1; s[i1] = t0; }
    __syncthreads();
    { float c1, s1; sincosf(theta_ps[0], &s1, &c1);
      float c2, s2; sincosf(a[7], &s2, &c2);
      float2 p1 = make_float2(c1, s1), p2 = make_float2(c2, s2);
      for (int i = tid; i < 1024; i += 256) {
          float2 t = s[i];
          if ((i >> 1) & 1) t = cmul(t, p1);
          if ((i >> 2) & 1) t = cmul(t, p2);
          s[i] = t;
      } }
    __syncthreads();
    apply_rot(s, 5, rot_p[0], rot_p[1], rot_p[2], tid);
    __syncthreads();
    apply_rot(s, 4, a[6], a[7], a[8], tid);
    __syncthreads();

    int wave = tid >> 6;
    for (int k = 0; k < 10; ++k) {
        int p = 9 - k;
        float part = 0.f;
        for (int q = tid; q < 512; q += 256) {
            int i0 = ((q >> p) << (p + 1)) | (q & ((1 << p) - 1));
            int i1 = i0 | (1 << p);
            float2 aa = s[i0], bb = s[i1];
            part += aa.x * bb.y - aa.y * bb.x;
        }
        part *= 2.f;
#pragma unroll
        for (int off = 32; off > 0; off >>= 1)
            part += __shfl_down(part, off, 64);
        if ((tid & 63) == 0) red[k * 4 + wave] = part;
    }
    __syncthreads();
    if (tid == 0) {
        float ev[10];
        float mx = -1e30f;
#pragma unroll
        for (int k = 0; k < 10; ++k) {
            ev[k] = red[k * 4] + red[k * 4 + 1] + red[k * 4 + 2] + red[k * 4 + 3];
            mx = fmaxf(mx, ev[k]);
        }
        float sum = 0.f;
#pragma unroll
        for (int k = 0; k < 10; ++k) sum += expf(ev[k] - mx);
        float lse = mx + logf(sum);
#pragma unroll
        for (int k = 0; k < 10; ++k) out[b * 10 + k] = ev[k] - lse;
    }
}

extern "C" void kernel_launch(void* const* d_in, const int* in_sizes, int n_in,
                              void* d_out, int out_size, void* d_ws, size_t ws_size,
                              hipStream_t stream)
{
    (void)in_sizes; (void)n_in; (void)out_size; (void)ws_size;
    const float* x    = (const float*)d_in[0];
    const float* c1w  = (const float*)d_in[1];
    const float* c1b  = (const float*)d_in[2];
    const float* c2w  = (const float*)d_in[3];
    const float* c2b  = (const float*)d_in[4];
    const float* f1w  = (const float*)d_in[5];
    const float* f1b  = (const float*)d_in[6];
    const float* f2w  = (const float*)d_in[7];
    const float* f2b  = (const float*)d_in[8];
    const float* th0  = (const float*)d_in[9];
    const float* trz  = (const float*)d_in[10];
    const float* tps  = (const float*)d_in[11];
    const float* rotp = (const float*)d_in[12];
    float* out = (float*)d_out;

    char* ws = (char*)d_ws;
    ushort* h1b    = (ushort*)(ws);                       // 88,604,672 B
    ushort* pooled = (ushort*)(ws + 88604672);            // 37,748,736 B
    ushort* wt2    = (ushort*)(ws + 126353408);           //     36,864 B
    ushort* wf1    = (ushort*)(ws + 126390272);           //  2,359,296 B
    float*  part   = (float*)(ws + 128749568);            //  4,194,304 B
    float*  fc1o   = (float*)(ws + 132943872);            //  1,048,576 B
    float*  ang    = (float*)(ws + 133992448);            //     81,920 B

    prep_kernel<<<4680, 256, 0, stream>>>(c2w, f1w, wt2, wf1);
    conv1_kernel<<<21632, 256, 0, stream>>>(x, c1w, c1b, h1b);
    conv2_banded<<<6144, 384, 0, stream>>>(h1b, wt2, c2b, pooled);
    fc1_mfma<<<dim3(64, 4), 256, 0, stream>>>(pooled, wf1, part);
    fc1_reduce_kernel<<<1024, 256, 0, stream>>>(part, f1b, fc1o);
    fc2_kernel<<<80, 256, 0, stream>>>(fc1o, f2w, f2b, ang);
    quantum_kernel<<<2048, 256, 0, stream>>>(ang, th0, trz, tps, rotp, out);
}

// Round 9
// 165.802 us; speedup vs baseline: 1.4391x; 1.1054x over previous
//
#include <hip/hip_runtime.h>
#include <math.h>

typedef short short8 __attribute__((ext_vector_type(8)));
typedef float f32x4 __attribute__((ext_vector_type(4)));
typedef float f32x16 __attribute__((ext_vector_type(16)));

#define GLB_CP(p) ((const __attribute__((address_space(1))) void*)(p))
#define LDS_CP(p) ((__attribute__((address_space(3))) void*)(p))

__device__ __forceinline__ float2 cmul(float2 a, float2 b) {
    return make_float2(a.x * b.x - a.y * b.y, a.x * b.y + a.y * b.x);
}

__device__ __forceinline__ ushort f2bf(float f) {
    uint u = __float_as_uint(f);
    uint r = (u + 0x7FFFu + ((u >> 16) & 1u)) >> 16;
    return (ushort)r;
}

// ---- prep: conv2 weights -> wt2[tap][icg][oc][ic8] bf16 ; fc1 weights -> bf16 ----
__global__ __launch_bounds__(256) void prep_kernel(
    const float* __restrict__ c2w, const float* __restrict__ f1w,
    ushort* __restrict__ wt2, ushort* __restrict__ wf1)
{
    int i = blockIdx.x * 256 + threadIdx.x;
    if (i < 18432) {
        int icl = i & 7;
        int t = i >> 3;
        int oc = t & 63;
        int t2 = t >> 6;
        int icg = t2 & 3;
        int tap = t2 >> 2;
        int ic = icg * 8 + icl;
        wt2[i] = f2bf(c2w[(oc * 32 + ic) * 9 + tap]);
    } else if (i < 18432 + 1179648) {
        int j = i - 18432;
        wf1[j] = f2bf(f1w[j]);
    }
}

// ---- conv1 + relu -> h1b[b][icg][pix][ic8] bf16 (fully parallel, r3-proven) ----
__global__ __launch_bounds__(256) void conv1_kernel(
    const float* __restrict__ x, const float* __restrict__ w1,
    const float* __restrict__ b1, ushort* __restrict__ h1b)
{
    __shared__ float wl[288];
    __shared__ float bl[32];
    int tid = threadIdx.x;
    for (int e = tid; e < 288; e += 256) wl[e] = w1[e];
    if (tid < 32) bl[tid] = b1[tid];
    __syncthreads();
    int e = blockIdx.x * 256 + tid;          // 2048*676*4 total, exact grid
    int icg = e & 3;
    int t = e >> 2;
    int pix = t % 676;
    int b = t / 676;
    int y = pix / 26, xc = pix % 26;
    const float* xp = x + b * 784 + y * 28 + xc;
    float in9[9];
#pragma unroll
    for (int ky = 0; ky < 3; ++ky)
#pragma unroll
        for (int kx = 0; kx < 3; ++kx) in9[ky * 3 + kx] = xp[ky * 28 + kx];
    short8 outv;
#pragma unroll
    for (int o = 0; o < 8; ++o) {
        int oc = icg * 8 + o;
        float acc = bl[oc];
#pragma unroll
        for (int k = 0; k < 9; ++k) acc = fmaf(in9[k], wl[oc * 9 + k], acc);
        outv[o] = (short)f2bf(fmaxf(acc, 0.f));
    }
    *(short8*)&h1b[((b * 4 + icg) * 676 + pix) * 8] = outv;
}

// ---- conv2 banded MFMA: swapped operands -> register-only 2x2 maxpool ----
__global__ __launch_bounds__(384, 4) void conv2_banded(
    const ushort* __restrict__ h1b, const ushort* __restrict__ wt2,
    const float* __restrict__ c2b, ushort* __restrict__ pooled)
{
    __shared__ __attribute__((aligned(16))) ushort in_lds[8704];   // [icg 4][260][ic8] + pad
    __shared__ __attribute__((aligned(16))) ushort wt_lds[16384];  // [tap 8][icg 4][oc 64][ic8]
    int bx = blockIdx.x;
    int b = bx / 3;
    int band = bx % 3;
    int r0 = band * 8;
    int tid = threadIdx.x;
    int wave = tid >> 6;
    int lane = tid & 63;
    int lo = lane & 31;
    int hi = lane >> 5;

    // async stage: 17 input chunks + 32 weight chunks (taps 0-7)
    for (int c = wave; c < 49; c += 6) {
        if (c < 17) {
            int e = c * 64 + lane;
            if (e > 1039) e = 1039;                    // clamp; pad slots get dup data
            int icg = e / 260;
            int rem = e - icg * 260;                   // row*26+col, band-local
            const ushort* src = h1b + ((size_t)(b * 4 + icg) * 676 + r0 * 26 + rem) * 8;
            __builtin_amdgcn_global_load_lds(GLB_CP(src), LDS_CP(in_lds + c * 512), 16, 0, 0);
        } else {
            int e = (c - 17) * 64 + lane;              // < 2048 exact
            const ushort* src = wt2 + e * 8;
            __builtin_amdgcn_global_load_lds(GLB_CP(src), LDS_CP(wt_lds + (c - 17) * 512), 16, 0, 0);
        }
    }

    // tap-8 weight fragments direct from global (L2-hot), issued early
    short8 w8[2][2];
#pragma unroll
    for (int ks = 0; ks < 2; ++ks)
#pragma unroll
        for (int m = 0; m < 2; ++m)
            w8[ks][m] = *(const short8*)(wt2 + (size_t)((32 + ks * 2 + hi) * 64 + m * 32 + lo) * 8);
    float bias0 = c2b[lo];
    float bias1 = c2b[lo + 32];
    __syncthreads();

    int rx = wave % 3, ry = wave / 3;        // region: 8 wide x 4 tall
    int xcoord = rx * 8 + (lo & 7);
    int ycoord = ry * 4 + (lo >> 3);         // band-local conv row 0..7
    int pbase = ycoord * 26 + xcoord;

    f32x16 acc0 = (f32x16)0.f, acc1 = (f32x16)0.f;

#pragma unroll
    for (int tap = 0; tap < 8; ++tap) {
        int off = (tap / 3) * 26 + (tap % 3);
#pragma unroll
        for (int ks = 0; ks < 2; ++ks) {
            short8 bf = *(const short8*)&in_lds[((ks * 2 + hi) * 260 + pbase + off) * 8];
            short8 a0 = *(const short8*)&wt_lds[((tap * 4 + ks * 2 + hi) * 64 + lo) * 8];
            short8 a1 = *(const short8*)&wt_lds[((tap * 4 + ks * 2 + hi) * 64 + 32 + lo) * 8];
            acc0 = __builtin_amdgcn_mfma_f32_32x32x16_bf16(bf, a0, acc0, 0, 0, 0);
            acc1 = __builtin_amdgcn_mfma_f32_32x32x16_bf16(bf, a1, acc1, 0, 0, 0);
        }
    }
    { // tap 8 from prefetched registers
        int off = 2 * 26 + 2;
#pragma unroll
        for (int ks = 0; ks < 2; ++ks) {
            short8 bf = *(const short8*)&in_lds[((ks * 2 + hi) * 260 + pbase + off) * 8];
            acc0 = __builtin_amdgcn_mfma_f32_32x32x16_bf16(bf, w8[ks][0], acc0, 0, 0, 0);
            acc1 = __builtin_amdgcn_mfma_f32_32x32x16_bf16(bf, w8[ks][1], acc1, 0, 0, 0);
        }
    }

    // register-only epilogue: 2x2 pool quadruple = regs {b,b+1,b+4,b+5}, b in {0,2,8,10}
    ushort* pout = pooled + (size_t)b * 9216;
    int pcolb = rx * 4 + 2 * hi;             // even; pack (p=0,p=1) into one uint
#pragma unroll
    for (int q = 0; q < 2; ++q) {
        int prow = band * 4 + ry * 2 + q;
        int base = 8 * q;
        float m00 = fmaxf(fmaxf(acc0[base], acc0[base + 1]), fmaxf(acc0[base + 4], acc0[base + 5]));
        float m01 = fmaxf(fmaxf(acc0[base + 2], acc0[base + 3]), fmaxf(acc0[base + 6], acc0[base + 7]));
        uint pk0 = (uint)f2bf(fmaxf(m00 + bias0, 0.f)) | ((uint)f2bf(fmaxf(m01 + bias0, 0.f)) << 16);
        *(uint*)&pout[lo * 144 + prow * 12 + pcolb] = pk0;
        float m10 = fmaxf(fmaxf(acc1[base], acc1[base + 1]), fmaxf(acc1[base + 4], acc1[base + 5]));
        float m11 = fmaxf(fmaxf(acc1[base + 2], acc1[base + 3]), fmaxf(acc1[base + 6], acc1[base + 7]));
        uint pk1 = (uint)f2bf(fmaxf(m10 + bias1, 0.f)) | ((uint)f2bf(fmaxf(m11 + bias1, 0.f)) << 16);
        *(uint*)&pout[(lo + 32) * 144 + prow * 12 + pcolb] = pk1;
    }
}

// ---- fc1 MFMA: pooled[2048,9216]bf16 x wf1[128,9216]bf16^T, 4-way K-split ----
__global__ __launch_bounds__(256) void fc1_mfma(
    const ushort* __restrict__ pooled, const ushort* __restrict__ wf1,
    float* __restrict__ part)
{
    int bx = blockIdx.x, by = blockIdx.y;
    int tid = threadIdx.x;
    int wid = tid >> 6, lane = tid & 63;
    int lo = lane & 15, hi = lane >> 4;
    int m0 = bx * 32;
    int kb = by * 2304;

    f32x4 acc[2][2];
#pragma unroll
    for (int mt = 0; mt < 2; ++mt)
#pragma unroll
        for (int j = 0; j < 2; ++j) acc[mt][j] = (f32x4)0.f;

    const ushort* arow0 = pooled + (size_t)(m0 + lo) * 9216 + kb + hi * 8;
    const ushort* arow1 = arow0 + 16 * 9216;
    const ushort* brow0 = wf1 + (size_t)(wid * 32 + lo) * 9216 + kb + hi * 8;
    const ushort* brow1 = brow0 + 16 * 9216;

    for (int kt = 0; kt < 72; ++kt) {
        short8 a0 = *(const short8*)(arow0 + kt * 32);
        short8 a1 = *(const short8*)(arow1 + kt * 32);
        short8 b0 = *(const short8*)(brow0 + kt * 32);
        short8 b1 = *(const short8*)(brow1 + kt * 32);
        acc[0][0] = __builtin_amdgcn_mfma_f32_16x16x32_bf16(a0, b0, acc[0][0], 0, 0, 0);
        acc[1][0] = __builtin_amdgcn_mfma_f32_16x16x32_bf16(a1, b0, acc[1][0], 0, 0, 0);
        acc[0][1] = __builtin_amdgcn_mfma_f32_16x16x32_bf16(a0, b1, acc[0][1], 0, 0, 0);
        acc[1][1] = __builtin_amdgcn_mfma_f32_16x16x32_bf16(a1, b1, acc[1][1], 0, 0, 0);
    }
    float* pp = part + (size_t)by * 262144;
#pragma unroll
    for (int mt = 0; mt < 2; ++mt)
#pragma unroll
        for (int j = 0; j < 2; ++j)
#pragma unroll
            for (int r = 0; r < 4; ++r)
                pp[(m0 + mt * 16 + hi * 4 + r) * 128 + wid * 32 + j * 16 + lo] = acc[mt][j][r];
}

__global__ __launch_bounds__(256) void fc1_reduce_kernel(
    const float* __restrict__ part, const float* __restrict__ bias,
    float* __restrict__ outp)
{
    int idx = blockIdx.x * 256 + threadIdx.x;   // < 262144
    float s = 0.f;
#pragma unroll
    for (int ks = 0; ks < 4; ++ks) s += part[ks * 262144 + idx];
    outp[idx] = fmaxf(s + bias[idx & 127], 0.f);
}

// ---- fc2 + sigmoid*2pi -> angles[2048,10] ----
__global__ __launch_bounds__(256) void fc2_kernel(
    const float* __restrict__ h, const float* __restrict__ w,
    const float* __restrict__ bias, float* __restrict__ ang)
{
    int idx = blockIdx.x * 256 + threadIdx.x;
    if (idx >= 20480) return;
    int b = idx / 10, n = idx % 10;
    const float* hp = h + b * 128;
    const float* wp = w + n * 128;
    float s = bias[n];
    for (int k = 0; k < 128; ++k) s = fmaf(hp[k], wp[k], s);
    ang[idx] = 6.28318530718f / (1.f + expf(-s));
}

// ---------------- quantum circuit + <Y_k> + log_softmax ----------------
__device__ __forceinline__ void apply_rot(float2* s, int p, float phi, float th,
                                          float om, int tid)
{
    float c, sn; sincosf(0.5f * th, &sn, &c);
    float A = 0.5f * (phi + om), Bv = 0.5f * (phi - om);
    float cA, sA; sincosf(A, &sA, &cA);
    float cB, sB; sincosf(Bv, &sB, &cB);
    float2 m00 = make_float2(cA * c, -sA * c);
    float2 m01 = make_float2(-cB * sn, -sB * sn);
    float2 m10 = make_float2(cB * sn, -sB * sn);
    float2 m11 = make_float2(cA * c, sA * c);
    for (int q = tid; q < 512; q += 256) {
        int i0 = ((q >> p) << (p + 1)) | (q & ((1 << p) - 1));
        int i1 = i0 | (1 << p);
        float2 aa = s[i0], bb = s[i1];
        s[i0] = make_float2(m00.x * aa.x - m00.y * aa.y + m01.x * bb.x - m01.y * bb.y,
                            m00.x * aa.y + m00.y * aa.x + m01.x * bb.y + m01.y * bb.x);
        s[i1] = make_float2(m10.x * aa.x - m10.y * aa.y + m11.x * bb.x - m11.y * bb.y,
                            m10.x * aa.y + m10.y * aa.x + m11.x * bb.y + m11.y * bb.x);
    }
}

__global__ __launch_bounds__(256) void quantum_kernel(
    const float* __restrict__ ang, const float* __restrict__ theta0,
    const float* __restrict__ theta_rz, const float* __restrict__ theta_ps,
    const float* __restrict__ rot_p, float* __restrict__ out)
{
    __shared__ float2 s[1024];
    __shared__ float red[40];
    int b = blockIdx.x;
    int tid = threadIdx.x;

    float a[10];
#pragma unroll
    for (int k = 0; k < 10; ++k) a[k] = ang[b * 10 + k];
    float th[10];
#pragma unroll
    for (int k = 0; k < 10; ++k) th[k] = theta0[k] + a[k];
    th[1] += a[1];
    th[5] -= 0.78539816339745f;   // RX(-pi/4) on wire 5

    float2 v[10][2];
#pragma unroll
    for (int k = 0; k < 10; ++k) {
        float c, sn; sincosf(0.5f * th[k], &sn, &c);
        v[k][0] = make_float2(c, 0.f);
        v[k][1] = make_float2(0.f, -sn);
    }
    { float c, sn; sincosf(0.5f * a[2], &sn, &c);
      float2 v0 = v[2][0], v1 = v[2][1];
      v[2][0] = make_float2(c * v0.x - sn * v1.x, c * v0.y - sn * v1.y);
      v[2][1] = make_float2(sn * v0.x + c * v1.x, sn * v0.y + c * v1.y); }
    { float c, sn; sincosf(0.5f * a[3], &sn, &c);
      v[3][0] = cmul(v[3][0], make_float2(c, -sn));
      v[3][1] = cmul(v[3][1], make_float2(c, sn)); }
    { float2 t = v[4][1]; v[4][1] = make_float2(-t.y, t.x); }
    { const float r = 0.70710678118655f;
      float2 t = v[5][1]; v[5][1] = make_float2(r * (t.x - t.y), r * (t.x + t.y)); }
    { float c, sn; sincosf(0.5f * theta_rz[0], &sn, &c);
      v[6][0] = cmul(v[6][0], make_float2(c, -sn));
      v[6][1] = cmul(v[6][1], make_float2(c, sn)); }
    { float2 p = v[7][0], q = v[7][1];
      v[7][0] = make_float2(0.5f * ((p.x - p.y) + (q.x + q.y)),
                            0.5f * ((p.x + p.y) + (q.y - q.x)));
      v[7][1] = make_float2(0.5f * ((p.x + p.y) + (q.x - q.y)),
                            0.5f * ((p.y - p.x) + (q.x + q.y))); }

    // product state init — COMPILE-TIME indices only (rule #20: no dynamic
    // array index -> keeps v[][] in VGPRs, no scratch)
    for (int i = tid; i < 1024; i += 256) {
        float2 c = ((i >> 9) & 1) ? v[0][1] : v[0][0];
#pragma unroll
        for (int k = 1; k < 10; ++k) {
            float2 vk = ((i >> (9 - k)) & 1) ? v[k][1] : v[k][0];
            c = cmul(c, vk);
        }
        s[i] = c;
    }
    __syncthreads();

    for (int i = tid; i < 1024; i += 256)
        if (((i >> 9) & 1) && ((i >> 4) & 1)) { s[i].x = -s[i].x; s[i].y = -s[i].y; }
    __syncthreads();
    { int j = tid;
      int i0 = 512 | ((j >> 4) << 5) | (j & 15);
      int i1 = i0 | 16;
      float2 t0 = s[i0], t1 = s[i1];
      s[i0] = t1; s[i1] = t0; }
    __syncthreads();
    { int j = tid;
      int i0 = 512 | ((j >> 4) << 5) | (j & 15);
      int i1 = i0 | 16;
      float2 t0 = s[i0], t1 = s[i1];
      s[i0] = make_float2(t1.y, -t1.x);
      s[i1] = make_float2(-t0.y, t0.x); }
    __syncthreads();
    { int j = tid;
      int i0 = (j & 1) | (((j >> 1) & 15) << 2) | (((j >> 5) & 7) << 7) | 64;
      int i1 = i0 | 2;
      float2 t0 = s[i0], t1 = s[i1];
      s[i0] = make_float2(t1.y, -t1.x);
      s[i1] = make_float2(-t0.y, t0.x); }
    __syncthreads();
    { int j = tid;
      int i0 = (j & 63) | 128 | (((j >> 6) & 3) << 8);
      int i1 = i0 ^ 0xC0;
      float2 t0 = s[i0], t1 = s[i1];
      s[i0] = t1; s[i1] = t0; }
    __syncthreads();
    if (tid < 128) {
      int j = tid;
      int i0 = (j & 7) | 16 | 32 | (((j >> 3) & 15) << 6);
      int i1 = i0 ^ 0x18;
      float2 t0 = s[i0], t1 = s[i1];
      s[i0] = t1; s[i1] = t0; }
    __syncthreads();
    if (tid < 128) {
      int j = tid;
      int i0 = (j & 1) | 2 | (((j >> 1) & 3) << 2) | 16 | (((j >> 3) & 15) << 5);
      int i1 = i0 | 512;
      float2 t0 = s[i0], t1 = s[i1];
      s[i0] = t1; s[i1] = t0; }
    __syncthreads();
    { float c1, s1; sincosf(theta_ps[0], &s1, &c1);
      float c2, s2; sincosf(a[7], &s2, &c2);
      float2 p1 = make_float2(c1, s1), p2 = make_float2(c2, s2);
      for (int i = tid; i < 1024; i += 256) {
          float2 t = s[i];
          if ((i >> 1) & 1) t = cmul(t, p1);
          if ((i >> 2) & 1) t = cmul(t, p2);
          s[i] = t;
      } }
    __syncthreads();
    apply_rot(s, 5, rot_p[0], rot_p[1], rot_p[2], tid);
    __syncthreads();
    apply_rot(s, 4, a[6], a[7], a[8], tid);
    __syncthreads();

    int wave = tid >> 6;
    for (int k = 0; k < 10; ++k) {
        int p = 9 - k;
        float part = 0.f;
        for (int q = tid; q < 512; q += 256) {
            int i0 = ((q >> p) << (p + 1)) | (q & ((1 << p) - 1));
            int i1 = i0 | (1 << p);
            float2 aa = s[i0], bb = s[i1];
            part += aa.x * bb.y - aa.y * bb.x;
        }
        part *= 2.f;
#pragma unroll
        for (int off = 32; off > 0; off >>= 1)
            part += __shfl_down(part, off, 64);
        if ((tid & 63) == 0) red[k * 4 + wave] = part;
    }
    __syncthreads();
    if (tid == 0) {
        float ev[10];
        float mx = -1e30f;
#pragma unroll
        for (int k = 0; k < 10; ++k) {
            ev[k] = red[k * 4] + red[k * 4 + 1] + red[k * 4 + 2] + red[k * 4 + 3];
            mx = fmaxf(mx, ev[k]);
        }
        float sum = 0.f;
#pragma unroll
        for (int k = 0; k < 10; ++k) sum += expf(ev[k] - mx);
        float lse = mx + logf(sum);
#pragma unroll
        for (int k = 0; k < 10; ++k) out[b * 10 + k] = ev[k] - lse;
    }
}

extern "C" void kernel_launch(void* const* d_in, const int* in_sizes, int n_in,
                              void* d_out, int out_size, void* d_ws, size_t ws_size,
                              hipStream_t stream)
{
    (void)in_sizes; (void)n_in; (void)out_size; (void)ws_size;
    const float* x    = (const float*)d_in[0];
    const float* c1w  = (const float*)d_in[1];
    const float* c1b  = (const float*)d_in[2];
    const float* c2w  = (const float*)d_in[3];
    const float* c2b  = (const float*)d_in[4];
    const float* f1w  = (const float*)d_in[5];
    const float* f1b  = (const float*)d_in[6];
    const float* f2w  = (const float*)d_in[7];
    const float* f2b  = (const float*)d_in[8];
    const float* th0  = (const float*)d_in[9];
    const float* trz  = (const float*)d_in[10];
    const float* tps  = (const float*)d_in[11];
    const float* rotp = (const float*)d_in[12];
    float* out = (float*)d_out;

    char* ws = (char*)d_ws;
    ushort* h1b    = (ushort*)(ws);                       // 88,604,672 B
    ushort* pooled = (ushort*)(ws + 88604672);            // 37,748,736 B
    ushort* wt2    = (ushort*)(ws + 126353408);           //     36,864 B
    ushort* wf1    = (ushort*)(ws + 126390272);           //  2,359,296 B
    float*  part   = (float*)(ws + 128749568);            //  4,194,304 B
    float*  fc1o   = (float*)(ws + 132943872);            //  1,048,576 B
    float*  ang    = (float*)(ws + 133992448);            //     81,920 B

    prep_kernel<<<4680, 256, 0, stream>>>(c2w, f1w, wt2, wf1);
    conv1_kernel<<<21632, 256, 0, stream>>>(x, c1w, c1b, h1b);
    conv2_banded<<<6144, 384, 0, stream>>>(h1b, wt2, c2b, pooled);
    fc1_mfma<<<dim3(64, 4), 256, 0, stream>>>(pooled, wf1, part);
    fc1_reduce_kernel<<<1024, 256, 0, stream>>>(part, f1b, fc1o);
    fc2_kernel<<<80, 256, 0, stream>>>(fc1o, f2w, f2b, ang);
    quantum_kernel<<<2048, 256, 0, stream>>>(ang, th0, trz, tps, rotp, out);
}

// Round 10
// 161.006 us; speedup vs baseline: 1.4820x; 1.0298x over previous
//
#include <hip/hip_runtime.h>
#include <math.h>

typedef short short8 __attribute__((ext_vector_type(8)));
typedef float f32x4 __attribute__((ext_vector_type(4)));
typedef float f32x16 __attribute__((ext_vector_type(16)));

#define GLB_CP(p) ((const __attribute__((address_space(1))) void*)(p))
#define LDS_CP(p) ((__attribute__((address_space(3))) void*)(p))

__device__ __forceinline__ float2 cmul(float2 a, float2 b) {
    return make_float2(a.x * b.x - a.y * b.y, a.x * b.y + a.y * b.x);
}

__device__ __forceinline__ ushort f2bf(float f) {
    uint u = __float_as_uint(f);
    uint r = (u + 0x7FFFu + ((u >> 16) & 1u)) >> 16;
    return (ushort)r;
}

// ---- prep: conv2 weights -> wt2[tap][icg][oc][ic8] bf16 ; fc1 weights -> bf16 ----
__global__ __launch_bounds__(256) void prep_kernel(
    const float* __restrict__ c2w, const float* __restrict__ f1w,
    ushort* __restrict__ wt2, ushort* __restrict__ wf1)
{
    int i = blockIdx.x * 256 + threadIdx.x;
    if (i < 18432) {
        int icl = i & 7;
        int t = i >> 3;
        int oc = t & 63;
        int t2 = t >> 6;
        int icg = t2 & 3;
        int tap = t2 >> 2;
        int ic = icg * 8 + icl;
        wt2[i] = f2bf(c2w[(oc * 32 + ic) * 9 + tap]);
    } else if (i < 18432 + 1179648) {
        int j = i - 18432;
        wf1[j] = f2bf(f1w[j]);
    }
}

// ---- conv1 + relu -> h1b[b][icg][pix][ic8] bf16 (fully parallel, r3-proven) ----
__global__ __launch_bounds__(256) void conv1_kernel(
    const float* __restrict__ x, const float* __restrict__ w1,
    const float* __restrict__ b1, ushort* __restrict__ h1b)
{
    __shared__ float wl[288];
    __shared__ float bl[32];
    int tid = threadIdx.x;
    for (int e = tid; e < 288; e += 256) wl[e] = w1[e];
    if (tid < 32) bl[tid] = b1[tid];
    __syncthreads();
    int e = blockIdx.x * 256 + tid;          // 2048*676*4 total, exact grid
    int icg = e & 3;
    int t = e >> 2;
    int pix = t % 676;
    int b = t / 676;
    int y = pix / 26, xc = pix % 26;
    const float* xp = x + b * 784 + y * 28 + xc;
    float in9[9];
#pragma unroll
    for (int ky = 0; ky < 3; ++ky)
#pragma unroll
        for (int kx = 0; kx < 3; ++kx) in9[ky * 3 + kx] = xp[ky * 28 + kx];
    short8 outv;
#pragma unroll
    for (int o = 0; o < 8; ++o) {
        int oc = icg * 8 + o;
        float acc = bl[oc];
#pragma unroll
        for (int k = 0; k < 9; ++k) acc = fmaf(in9[k], wl[oc * 9 + k], acc);
        outv[o] = (short)f2bf(fmaxf(acc, 0.f));
    }
    *(short8*)&h1b[((b * 4 + icg) * 676 + pix) * 8] = outv;
}

// ---- conv2: one block per image, 2-phase pipelined bands, register maxpool ----
// 6 waves; weights staged ONCE (36.9 KB); input band double-buffer (2x17.4 KB).
// Loop: issue band+1 loads -> compute band (36 MFMA/wave) -> epilogue -> barrier.
// LDS total 71,680 B -> 2 blocks/CU.
__global__ __launch_bounds__(384, 3) void conv2_img(
    const ushort* __restrict__ h1b, const ushort* __restrict__ wt2,
    const float* __restrict__ c2b, ushort* __restrict__ pooled)
{
    __shared__ __attribute__((aligned(16))) ushort wt_lds[18432];   // [tap 9][icg 4][oc 64][ic8]
    __shared__ __attribute__((aligned(16))) ushort in_lds[2][8704]; // [icg 4][260][ic8] + pad
    int b = blockIdx.x;
    int tid = threadIdx.x;
    int wave = tid >> 6;
    int lane = tid & 63;
    int lo = lane & 31;
    int hi = lane >> 5;

    // initial stage: all 9 taps of weights (36 chunks) + band-0 input (17 chunks)
    for (int c = wave; c < 36; c += 6) {
        const ushort* src = wt2 + (size_t)(c * 64 + lane) * 8;
        __builtin_amdgcn_global_load_lds(GLB_CP(src), LDS_CP(wt_lds + c * 512), 16, 0, 0);
    }
    {
        const ushort* base = h1b + (size_t)b * 21632;   // 4*676*8
        for (int c = wave; c < 17; c += 6) {
            int e = c * 64 + lane;
            if (e > 1039) e = 1039;
            int icg = e / 260;
            int rem = e - icg * 260;
            const ushort* src = base + ((size_t)icg * 676 + rem) * 8;
            __builtin_amdgcn_global_load_lds(GLB_CP(src), LDS_CP(in_lds[0] + c * 512), 16, 0, 0);
        }
    }
    float bias0 = c2b[lo];
    float bias1 = c2b[lo + 32];
    __syncthreads();

    int rx = wave % 3, ry = wave / 3;        // region: 8 wide x 4 tall
    int xcoord = rx * 8 + (lo & 7);
    int ycoord = ry * 4 + (lo >> 3);         // band-local conv row 0..7
    int pbase = ycoord * 26 + xcoord;
    ushort* pout = pooled + (size_t)b * 9216;
    int pcolb = rx * 4 + 2 * hi;

#pragma unroll
    for (int band = 0; band < 3; ++band) {
        // issue next band's loads into the other buffer (hidden under this band's MFMA)
        if (band < 2) {
            const ushort* base = h1b + (size_t)b * 21632 + (size_t)(band + 1) * 8 * 26 * 8;
            ushort* dst = in_lds[(band + 1) & 1];
            for (int c = wave; c < 17; c += 6) {
                int e = c * 64 + lane;
                if (e > 1039) e = 1039;
                int icg = e / 260;
                int rem = e - icg * 260;
                const ushort* src = base + ((size_t)icg * 676 + rem) * 8;
                __builtin_amdgcn_global_load_lds(GLB_CP(src), LDS_CP(dst + c * 512), 16, 0, 0);
            }
        }

        const ushort* ib = in_lds[band & 1];
        f32x16 acc0 = (f32x16)0.f, acc1 = (f32x16)0.f;
#pragma unroll
        for (int tap = 0; tap < 9; ++tap) {
            int off = (tap / 3) * 26 + (tap % 3);
#pragma unroll
            for (int ks = 0; ks < 2; ++ks) {
                short8 bf = *(const short8*)&ib[((ks * 2 + hi) * 260 + pbase + off) * 8];
                short8 a0 = *(const short8*)&wt_lds[((tap * 4 + ks * 2 + hi) * 64 + lo) * 8];
                short8 a1 = *(const short8*)&wt_lds[((tap * 4 + ks * 2 + hi) * 64 + 32 + lo) * 8];
                acc0 = __builtin_amdgcn_mfma_f32_32x32x16_bf16(bf, a0, acc0, 0, 0, 0);
                acc1 = __builtin_amdgcn_mfma_f32_32x32x16_bf16(bf, a1, acc1, 0, 0, 0);
            }
        }

        // register-only epilogue: pool quadruple = regs {b,b+1,b+4,b+5}, b in {0,2,8,10}
#pragma unroll
        for (int q = 0; q < 2; ++q) {
            int prow = band * 4 + ry * 2 + q;
            int base = 8 * q;
            float m00 = fmaxf(fmaxf(acc0[base], acc0[base + 1]), fmaxf(acc0[base + 4], acc0[base + 5]));
            float m01 = fmaxf(fmaxf(acc0[base + 2], acc0[base + 3]), fmaxf(acc0[base + 6], acc0[base + 7]));
            uint pk0 = (uint)f2bf(fmaxf(m00 + bias0, 0.f)) | ((uint)f2bf(fmaxf(m01 + bias0, 0.f)) << 16);
            *(uint*)&pout[lo * 144 + prow * 12 + pcolb] = pk0;
            float m10 = fmaxf(fmaxf(acc1[base], acc1[base + 1]), fmaxf(acc1[base + 4], acc1[base + 5]));
            float m11 = fmaxf(fmaxf(acc1[base + 2], acc1[base + 3]), fmaxf(acc1[base + 6], acc1[base + 7]));
            uint pk1 = (uint)f2bf(fmaxf(m10 + bias1, 0.f)) | ((uint)f2bf(fmaxf(m11 + bias1, 0.f)) << 16);
            *(uint*)&pout[(lo + 32) * 144 + prow * 12 + pcolb] = pk1;
        }
        __syncthreads();   // drains next band's loads; guards buffer reuse
    }
}

// ---- fc1 MFMA: pooled[2048,9216]bf16 x wf1[128,9216]bf16^T, 4-way K-split ----
__global__ __launch_bounds__(256) void fc1_mfma(
    const ushort* __restrict__ pooled, const ushort* __restrict__ wf1,
    float* __restrict__ part)
{
    int bx = blockIdx.x, by = blockIdx.y;
    int tid = threadIdx.x;
    int wid = tid >> 6, lane = tid & 63;
    int lo = lane & 15, hi = lane >> 4;
    int m0 = bx * 32;
    int kb = by * 2304;

    f32x4 acc[2][2];
#pragma unroll
    for (int mt = 0; mt < 2; ++mt)
#pragma unroll
        for (int j = 0; j < 2; ++j) acc[mt][j] = (f32x4)0.f;

    const ushort* arow0 = pooled + (size_t)(m0 + lo) * 9216 + kb + hi * 8;
    const ushort* arow1 = arow0 + 16 * 9216;
    const ushort* brow0 = wf1 + (size_t)(wid * 32 + lo) * 9216 + kb + hi * 8;
    const ushort* brow1 = brow0 + 16 * 9216;

    for (int kt = 0; kt < 72; ++kt) {
        short8 a0 = *(const short8*)(arow0 + kt * 32);
        short8 a1 = *(const short8*)(arow1 + kt * 32);
        short8 b0 = *(const short8*)(brow0 + kt * 32);
        short8 b1 = *(const short8*)(brow1 + kt * 32);
        acc[0][0] = __builtin_amdgcn_mfma_f32_16x16x32_bf16(a0, b0, acc[0][0], 0, 0, 0);
        acc[1][0] = __builtin_amdgcn_mfma_f32_16x16x32_bf16(a1, b0, acc[1][0], 0, 0, 0);
        acc[0][1] = __builtin_amdgcn_mfma_f32_16x16x32_bf16(a0, b1, acc[0][1], 0, 0, 0);
        acc[1][1] = __builtin_amdgcn_mfma_f32_16x16x32_bf16(a1, b1, acc[1][1], 0, 0, 0);
    }
    float* pp = part + (size_t)by * 262144;
#pragma unroll
    for (int mt = 0; mt < 2; ++mt)
#pragma unroll
        for (int j = 0; j < 2; ++j)
#pragma unroll
            for (int r = 0; r < 4; ++r)
                pp[(m0 + mt * 16 + hi * 4 + r) * 128 + wid * 32 + j * 16 + lo] = acc[mt][j][r];
}

__global__ __launch_bounds__(256) void fc1_reduce_kernel(
    const float* __restrict__ part, const float* __restrict__ bias,
    float* __restrict__ outp)
{
    int idx = blockIdx.x * 256 + threadIdx.x;   // < 262144
    float s = 0.f;
#pragma unroll
    for (int ks = 0; ks < 4; ++ks) s += part[ks * 262144 + idx];
    outp[idx] = fmaxf(s + bias[idx & 127], 0.f);
}

// ---- fc2 + sigmoid*2pi -> angles[2048,10] ----
__global__ __launch_bounds__(256) void fc2_kernel(
    const float* __restrict__ h, const float* __restrict__ w,
    const float* __restrict__ bias, float* __restrict__ ang)
{
    int idx = blockIdx.x * 256 + threadIdx.x;
    if (idx >= 20480) return;
    int b = idx / 10, n = idx % 10;
    const float* hp = h + b * 128;
    const float* wp = w + n * 128;
    float s = bias[n];
    for (int k = 0; k < 128; ++k) s = fmaf(hp[k], wp[k], s);
    ang[idx] = 6.28318530718f / (1.f + expf(-s));
}

// ---------------- quantum circuit + <Y_k> + log_softmax ----------------
__device__ __forceinline__ void apply_rot(float2* s, int p, float phi, float th,
                                          float om, int tid)
{
    float c, sn; sincosf(0.5f * th, &sn, &c);
    float A = 0.5f * (phi + om), Bv = 0.5f * (phi - om);
    float cA, sA; sincosf(A, &sA, &cA);
    float cB, sB; sincosf(Bv, &sB, &cB);
    float2 m00 = make_float2(cA * c, -sA * c);
    float2 m01 = make_float2(-cB * sn, -sB * sn);
    float2 m10 = make_float2(cB * sn, -sB * sn);
    float2 m11 = make_float2(cA * c, sA * c);
    for (int q = tid; q < 512; q += 256) {
        int i0 = ((q >> p) << (p + 1)) | (q & ((1 << p) - 1));
        int i1 = i0 | (1 << p);
        float2 aa = s[i0], bb = s[i1];
        s[i0] = make_float2(m00.x * aa.x - m00.y * aa.y + m01.x * bb.x - m01.y * bb.y,
                            m00.x * aa.y + m00.y * aa.x + m01.x * bb.y + m01.y * bb.x);
        s[i1] = make_float2(m10.x * aa.x - m10.y * aa.y + m11.x * bb.x - m11.y * bb.y,
                            m10.x * aa.y + m10.y * aa.x + m11.x * bb.y + m11.y * bb.x);
    }
}

__global__ __launch_bounds__(256) void quantum_kernel(
    const float* __restrict__ ang, const float* __restrict__ theta0,
    const float* __restrict__ theta_rz, const float* __restrict__ theta_ps,
    const float* __restrict__ rot_p, float* __restrict__ out)
{
    __shared__ float2 s[1024];
    __shared__ float red[40];
    int b = blockIdx.x;
    int tid = threadIdx.x;

    float a[10];
#pragma unroll
    for (int k = 0; k < 10; ++k) a[k] = ang[b * 10 + k];
    float th[10];
#pragma unroll
    for (int k = 0; k < 10; ++k) th[k] = theta0[k] + a[k];
    th[1] += a[1];
    th[5] -= 0.78539816339745f;   // RX(-pi/4) on wire 5

    float2 v[10][2];
#pragma unroll
    for (int k = 0; k < 10; ++k) {
        float c, sn; sincosf(0.5f * th[k], &sn, &c);
        v[k][0] = make_float2(c, 0.f);
        v[k][1] = make_float2(0.f, -sn);
    }
    { float c, sn; sincosf(0.5f * a[2], &sn, &c);
      float2 v0 = v[2][0], v1 = v[2][1];
      v[2][0] = make_float2(c * v0.x - sn * v1.x, c * v0.y - sn * v1.y);
      v[2][1] = make_float2(sn * v0.x + c * v1.x, sn * v0.y + c * v1.y); }
    { float c, sn; sincosf(0.5f * a[3], &sn, &c);
      v[3][0] = cmul(v[3][0], make_float2(c, -sn));
      v[3][1] = cmul(v[3][1], make_float2(c, sn)); }
    { float2 t = v[4][1]; v[4][1] = make_float2(-t.y, t.x); }
    { const float r = 0.70710678118655f;
      float2 t = v[5][1]; v[5][1] = make_float2(r * (t.x - t.y), r * (t.x + t.y)); }
    { float c, sn; sincosf(0.5f * theta_rz[0], &sn, &c);
      v[6][0] = cmul(v[6][0], make_float2(c, -sn));
      v[6][1] = cmul(v[6][1], make_float2(c, sn)); }
    { float2 p = v[7][0], q = v[7][1];
      v[7][0] = make_float2(0.5f * ((p.x - p.y) + (q.x + q.y)),
                            0.5f * ((p.x + p.y) + (q.y - q.x)));
      v[7][1] = make_float2(0.5f * ((p.x + p.y) + (q.x - q.y)),
                            0.5f * ((p.y - p.x) + (q.x + q.y))); }

    // product state init — compile-time indices only (no scratch)
    for (int i = tid; i < 1024; i += 256) {
        float2 c = ((i >> 9) & 1) ? v[0][1] : v[0][0];
#pragma unroll
        for (int k = 1; k < 10; ++k) {
            float2 vk = ((i >> (9 - k)) & 1) ? v[k][1] : v[k][0];
            c = cmul(c, vk);
        }
        s[i] = c;
    }
    __syncthreads();

    for (int i = tid; i < 1024; i += 256)
        if (((i >> 9) & 1) && ((i >> 4) & 1)) { s[i].x = -s[i].x; s[i].y = -s[i].y; }
    __syncthreads();
    { int j = tid;
      int i0 = 512 | ((j >> 4) << 5) | (j & 15);
      int i1 = i0 | 16;
      float2 t0 = s[i0], t1 = s[i1];
      s[i0] = t1; s[i1] = t0; }
    __syncthreads();
    { int j = tid;
      int i0 = 512 | ((j >> 4) << 5) | (j & 15);
      int i1 = i0 | 16;
      float2 t0 = s[i0], t1 = s[i1];
      s[i0] = make_float2(t1.y, -t1.x);
      s[i1] = make_float2(-t0.y, t0.x); }
    __syncthreads();
    { int j = tid;
      int i0 = (j & 1) | (((j >> 1) & 15) << 2) | (((j >> 5) & 7) << 7) | 64;
      int i1 = i0 | 2;
      float2 t0 = s[i0], t1 = s[i1];
      s[i0] = make_float2(t1.y, -t1.x);
      s[i1] = make_float2(-t0.y, t0.x); }
    __syncthreads();
    { int j = tid;
      int i0 = (j & 63) | 128 | (((j >> 6) & 3) << 8);
      int i1 = i0 ^ 0xC0;
      float2 t0 = s[i0], t1 = s[i1];
      s[i0] = t1; s[i1] = t0; }
    __syncthreads();
    if (tid < 128) {
      int j = tid;
      int i0 = (j & 7) | 16 | 32 | (((j >> 3) & 15) << 6);
      int i1 = i0 ^ 0x18;
      float2 t0 = s[i0], t1 = s[i1];
      s[i0] = t1; s[i1] = t0; }
    __syncthreads();
    if (tid < 128) {
      int j = tid;
      int i0 = (j & 1) | 2 | (((j >> 1) & 3) << 2) | 16 | (((j >> 3) & 15) << 5);
      int i1 = i0 | 512;
      float2 t0 = s[i0], t1 = s[i1];
      s[i0] = t1; s[i1] = t0; }
    __syncthreads();
    { float c1, s1; sincosf(theta_ps[0], &s1, &c1);
      float c2, s2; sincosf(a[7], &s2, &c2);
      float2 p1 = make_float2(c1, s1), p2 = make_float2(c2, s2);
      for (int i = tid; i < 1024; i += 256) {
          float2 t = s[i];
          if ((i >> 1) & 1) t = cmul(t, p1);
          if ((i >> 2) & 1) t = cmul(t, p2);
          s[i] = t;
      } }
    __syncthreads();
    apply_rot(s, 5, rot_p[0], rot_p[1], rot_p[2], tid);
    __syncthreads();
    apply_rot(s, 4, a[6], a[7], a[8], tid);
    __syncthreads();

    int wave = tid >> 6;
    for (int k = 0; k < 10; ++k) {
        int p = 9 - k;
        float part = 0.f;
        for (int q = tid; q < 512; q += 256) {
            int i0 = ((q >> p) << (p + 1)) | (q & ((1 << p) - 1));
            int i1 = i0 | (1 << p);
            float2 aa = s[i0], bb = s[i1];
            part += aa.x * bb.y - aa.y * bb.x;
        }
        part *= 2.f;
#pragma unroll
        for (int off = 32; off > 0; off >>= 1)
            part += __shfl_down(part, off, 64);
        if ((tid & 63) == 0) red[k * 4 + wave] = part;
    }
    __syncthreads();
    if (tid == 0) {
        float ev[10];
        float mx = -1e30f;
#pragma unroll
        for (int k = 0; k < 10; ++k) {
            ev[k] = red[k * 4] + red[k * 4 + 1] + red[k * 4 + 2] + red[k * 4 + 3];
            mx = fmaxf(mx, ev[k]);
        }
        float sum = 0.f;
#pragma unroll
        for (int k = 0; k < 10; ++k) sum += expf(ev[k] - mx);
        float lse = mx + logf(sum);
#pragma unroll
        for (int k = 0; k < 10; ++k) out[b * 10 + k] = ev[k] - lse;
    }
}

extern "C" void kernel_launch(void* const* d_in, const int* in_sizes, int n_in,
                              void* d_out, int out_size, void* d_ws, size_t ws_size,
                              hipStream_t stream)
{
    (void)in_sizes; (void)n_in; (void)out_size; (void)ws_size;
    const float* x    = (const float*)d_in[0];
    const float* c1w  = (const float*)d_in[1];
    const float* c1b  = (const float*)d_in[2];
    const float* c2w  = (const float*)d_in[3];
    const float* c2b  = (const float*)d_in[4];
    const float* f1w  = (const float*)d_in[5];
    const float* f1b  = (const float*)d_in[6];
    const float* f2w  = (const float*)d_in[7];
    const float* f2b  = (const float*)d_in[8];
    const float* th0  = (const float*)d_in[9];
    const float* trz  = (const float*)d_in[10];
    const float* tps  = (const float*)d_in[11];
    const float* rotp = (const float*)d_in[12];
    float* out = (float*)d_out;

    char* ws = (char*)d_ws;
    ushort* h1b    = (ushort*)(ws);                       // 88,604,672 B
    ushort* pooled = (ushort*)(ws + 88604672);            // 37,748,736 B
    ushort* wt2    = (ushort*)(ws + 126353408);           //     36,864 B
    ushort* wf1    = (ushort*)(ws + 126390272);           //  2,359,296 B
    float*  part   = (float*)(ws + 128749568);            //  4,194,304 B
    float*  fc1o   = (float*)(ws + 132943872);            //  1,048,576 B
    float*  ang    = (float*)(ws + 133992448);            //     81,920 B

    prep_kernel<<<4680, 256, 0, stream>>>(c2w, f1w, wt2, wf1);
    conv1_kernel<<<21632, 256, 0, stream>>>(x, c1w, c1b, h1b);
    conv2_img<<<2048, 384, 0, stream>>>(h1b, wt2, c2b, pooled);
    fc1_mfma<<<dim3(64, 4), 256, 0, stream>>>(pooled, wf1, part);
    fc1_reduce_kernel<<<1024, 256, 0, stream>>>(part, f1b, fc1o);
    fc2_kernel<<<80, 256, 0, stream>>>(fc1o, f2w, f2b, ang);
    quantum_kernel<<<2048, 256, 0, stream>>>(ang, th0, trz, tps, rotp, out);
}

// Round 11
// 155.047 us; speedup vs baseline: 1.5389x; 1.0384x over previous
//
#include <hip/hip_runtime.h>
#include <math.h>

typedef short short8 __attribute__((ext_vector_type(8)));
typedef float f32x4 __attribute__((ext_vector_type(4)));
typedef float f32x16 __attribute__((ext_vector_type(16)));

#define GLB_CP(p) ((const __attribute__((address_space(1))) void*)(p))
#define LDS_CP(p) ((__attribute__((address_space(3))) void*)(p))

__device__ __forceinline__ float2 cmul(float2 a, float2 b) {
    return make_float2(a.x * b.x - a.y * b.y, a.x * b.y + a.y * b.x);
}

__device__ __forceinline__ ushort f2bf(float f) {
    uint u = __float_as_uint(f);
    uint r = (u + 0x7FFFu + ((u >> 16) & 1u)) >> 16;
    return (ushort)r;
}

// ---- prep: conv2 weights -> wt2[tap][icg][oc][ic8] bf16 ; fc1 weights -> bf16 ----
__global__ __launch_bounds__(256) void prep_kernel(
    const float* __restrict__ c2w, const float* __restrict__ f1w,
    ushort* __restrict__ wt2, ushort* __restrict__ wf1)
{
    int i = blockIdx.x * 256 + threadIdx.x;
    if (i < 18432) {
        int icl = i & 7;
        int t = i >> 3;
        int oc = t & 63;
        int t2 = t >> 6;
        int icg = t2 & 3;
        int tap = t2 >> 2;
        int ic = icg * 8 + icl;
        wt2[i] = f2bf(c2w[(oc * 32 + ic) * 9 + tap]);
    } else if (i < 18432 + 1179648) {
        int j = i - 18432;
        wf1[j] = f2bf(f1w[j]);
    }
}

// ---- conv1 + relu -> h1b[b][icg][pix][ic8] bf16 (fully parallel, r3-proven) ----
__global__ __launch_bounds__(256) void conv1_kernel(
    const float* __restrict__ x, const float* __restrict__ w1,
    const float* __restrict__ b1, ushort* __restrict__ h1b)
{
    __shared__ float wl[288];
    __shared__ float bl[32];
    int tid = threadIdx.x;
    for (int e = tid; e < 288; e += 256) wl[e] = w1[e];
    if (tid < 32) bl[tid] = b1[tid];
    __syncthreads();
    int e = blockIdx.x * 256 + tid;          // 2048*676*4 total, exact grid
    int icg = e & 3;
    int t = e >> 2;
    int pix = t % 676;
    int b = t / 676;
    int y = pix / 26, xc = pix % 26;
    const float* xp = x + b * 784 + y * 28 + xc;
    float in9[9];
#pragma unroll
    for (int ky = 0; ky < 3; ++ky)
#pragma unroll
        for (int kx = 0; kx < 3; ++kx) in9[ky * 3 + kx] = xp[ky * 28 + kx];
    short8 outv;
#pragma unroll
    for (int o = 0; o < 8; ++o) {
        int oc = icg * 8 + o;
        float acc = bl[oc];
#pragma unroll
        for (int k = 0; k < 9; ++k) acc = fmaf(in9[k], wl[oc * 9 + k], acc);
        outv[o] = (short)f2bf(fmaxf(acc, 0.f));
    }
    *(short8*)&h1b[((b * 4 + icg) * 676 + pix) * 8] = outv;
}

// ---- conv2 persistent: 256 blocks x 8 images; weights once; full-image dbuf ----
// 6 waves; wave owns 3 regions (8x4 px) -> per (tap,ks): 2 A-reads + 3 B-reads
// feed 6 MFMAs (90 ds_read_b128 / wave / image vs 162 in the banded version).
// LDS: wt 36,864 + 2 x 44,032 input = 124,928 B -> exactly 1 block/CU.
#define EPILOG(ACC0, ACC1, RX, RY)                                                         \
    {                                                                                      \
        int pcolb = (RX) * 4 + 2 * hi;                                                     \
        _Pragma("unroll")                                                                  \
        for (int q = 0; q < 2; ++q) {                                                      \
            int prow = (RY) * 2 + q;                                                       \
            int bs = 8 * q;                                                                \
            float m00 = fmaxf(fmaxf(ACC0[bs], ACC0[bs + 1]), fmaxf(ACC0[bs + 4], ACC0[bs + 5])); \
            float m01 = fmaxf(fmaxf(ACC0[bs + 2], ACC0[bs + 3]), fmaxf(ACC0[bs + 6], ACC0[bs + 7])); \
            uint pk0 = (uint)f2bf(fmaxf(m00 + bias0, 0.f)) | ((uint)f2bf(fmaxf(m01 + bias0, 0.f)) << 16); \
            *(uint*)&pout[lo * 144 + prow * 12 + pcolb] = pk0;                             \
            float m10 = fmaxf(fmaxf(ACC1[bs], ACC1[bs + 1]), fmaxf(ACC1[bs + 4], ACC1[bs + 5])); \
            float m11 = fmaxf(fmaxf(ACC1[bs + 2], ACC1[bs + 3]), fmaxf(ACC1[bs + 6], ACC1[bs + 7])); \
            uint pk1 = (uint)f2bf(fmaxf(m10 + bias1, 0.f)) | ((uint)f2bf(fmaxf(m11 + bias1, 0.f)) << 16); \
            *(uint*)&pout[(lo + 32) * 144 + prow * 12 + pcolb] = pk1;                      \
        }                                                                                  \
    }

__global__ __launch_bounds__(384, 2) void conv2_persist(
    const ushort* __restrict__ h1b, const ushort* __restrict__ wt2,
    const float* __restrict__ c2b, ushort* __restrict__ pooled)
{
    __shared__ __attribute__((aligned(16))) ushort wt_lds[18432];     // [tap9][icg4][oc64][ic8]
    __shared__ __attribute__((aligned(16))) ushort in_lds[2][22016];  // [icg4][pix676][ic8] + pad
    int cu = blockIdx.x;              // 0..255, 8 images each
    int tid = threadIdx.x;
    int wave = tid >> 6;
    int lane = tid & 63;
    int lo = lane & 31;
    int hi = lane >> 5;

    // stage weights once (36 chunks) + image-0 input (43 chunks)
    for (int c = wave; c < 36; c += 6) {
        const ushort* src = wt2 + (size_t)(c * 64 + lane) * 8;
        __builtin_amdgcn_global_load_lds(GLB_CP(src), LDS_CP(wt_lds + c * 512), 16, 0, 0);
    }
    {
        const ushort* base = h1b + (size_t)(cu * 8) * 21632;
        for (int c = wave; c < 43; c += 6) {
            int e = c * 64 + lane;
            if (e > 2703) e = 2703;               // clamp; pad slots get dup data
            __builtin_amdgcn_global_load_lds(GLB_CP(base + (size_t)e * 8),
                                             LDS_CP(in_lds[0] + c * 512), 16, 0, 0);
        }
    }
    float bias0 = c2b[lo];
    float bias1 = c2b[lo + 32];
    __syncthreads();

    // 3 regions per wave: r = wave + 6*i; region = 8 wide x 4 tall
    int pb[3];
#pragma unroll
    for (int i = 0; i < 3; ++i) {
        int r = wave + 6 * i;
        int rx = r % 3, ry = r / 3;
        int xcoord = rx * 8 + (lo & 7);
        int ycoord = ry * 4 + (lo >> 3);          // full-image conv row 0..23
        pb[i] = ycoord * 26 + xcoord;
    }
    int rx0 = wave % 3, ry0 = wave / 3;
    int rx1 = (wave + 6) % 3, ry1 = (wave + 6) / 3;
    int rx2 = (wave + 12) % 3, ry2 = (wave + 12) / 3;

    for (int j = 0; j < 8; ++j) {
        // prefetch next image into alternate buffer (hidden under this image's MFMA)
        if (j < 7) {
            const ushort* base = h1b + (size_t)(cu * 8 + j + 1) * 21632;
            ushort* dst = in_lds[(j + 1) & 1];
            for (int c = wave; c < 43; c += 6) {
                int e = c * 64 + lane;
                if (e > 2703) e = 2703;
                __builtin_amdgcn_global_load_lds(GLB_CP(base + (size_t)e * 8),
                                                 LDS_CP(dst + c * 512), 16, 0, 0);
            }
        }

        const ushort* ib = in_lds[j & 1];
        f32x16 aA0 = (f32x16)0.f, aA1 = (f32x16)0.f;
        f32x16 aB0 = (f32x16)0.f, aB1 = (f32x16)0.f;
        f32x16 aC0 = (f32x16)0.f, aC1 = (f32x16)0.f;

#pragma unroll
        for (int tap = 0; tap < 9; ++tap) {
            int off = (tap / 3) * 26 + (tap % 3);
#pragma unroll
            for (int ks = 0; ks < 2; ++ks) {
                const ushort* wp = &wt_lds[((tap * 4 + ks * 2 + hi) * 64) * 8];
                short8 a0 = *(const short8*)(wp + lo * 8);
                short8 a1 = *(const short8*)(wp + (32 + lo) * 8);
                const ushort* ip = &ib[((ks * 2 + hi) * 676 + off) * 8];
                short8 b0 = *(const short8*)(ip + pb[0] * 8);
                short8 b1 = *(const short8*)(ip + pb[1] * 8);
                short8 b2 = *(const short8*)(ip + pb[2] * 8);
                aA0 = __builtin_amdgcn_mfma_f32_32x32x16_bf16(b0, a0, aA0, 0, 0, 0);
                aA1 = __builtin_amdgcn_mfma_f32_32x32x16_bf16(b0, a1, aA1, 0, 0, 0);
                aB0 = __builtin_amdgcn_mfma_f32_32x32x16_bf16(b1, a0, aB0, 0, 0, 0);
                aB1 = __builtin_amdgcn_mfma_f32_32x32x16_bf16(b1, a1, aB1, 0, 0, 0);
                aC0 = __builtin_amdgcn_mfma_f32_32x32x16_bf16(b2, a0, aC0, 0, 0, 0);
                aC1 = __builtin_amdgcn_mfma_f32_32x32x16_bf16(b2, a1, aC1, 0, 0, 0);
            }
        }

        // register-only epilogue (r8-proven), prow = ry*2+q over full 12x12 pool grid
        ushort* pout = pooled + (size_t)(cu * 8 + j) * 9216;
        EPILOG(aA0, aA1, rx0, ry0)
        EPILOG(aB0, aB1, rx1, ry1)
        EPILOG(aC0, aC1, rx2, ry2)
        __syncthreads();   // drains next image's DMA; guards buffer reuse
    }
}

// ---- fc1 MFMA: pooled[2048,9216]bf16 x wf1[128,9216]bf16^T, 4-way K-split ----
__global__ __launch_bounds__(256) void fc1_mfma(
    const ushort* __restrict__ pooled, const ushort* __restrict__ wf1,
    float* __restrict__ part)
{
    int bx = blockIdx.x, by = blockIdx.y;
    int tid = threadIdx.x;
    int wid = tid >> 6, lane = tid & 63;
    int lo = lane & 15, hi = lane >> 4;
    int m0 = bx * 32;
    int kb = by * 2304;

    f32x4 acc[2][2];
#pragma unroll
    for (int mt = 0; mt < 2; ++mt)
#pragma unroll
        for (int j = 0; j < 2; ++j) acc[mt][j] = (f32x4)0.f;

    const ushort* arow0 = pooled + (size_t)(m0 + lo) * 9216 + kb + hi * 8;
    const ushort* arow1 = arow0 + 16 * 9216;
    const ushort* brow0 = wf1 + (size_t)(wid * 32 + lo) * 9216 + kb + hi * 8;
    const ushort* brow1 = brow0 + 16 * 9216;

    for (int kt = 0; kt < 72; ++kt) {
        short8 a0 = *(const short8*)(arow0 + kt * 32);
        short8 a1 = *(const short8*)(arow1 + kt * 32);
        short8 b0 = *(const short8*)(brow0 + kt * 32);
        short8 b1 = *(const short8*)(brow1 + kt * 32);
        acc[0][0] = __builtin_amdgcn_mfma_f32_16x16x32_bf16(a0, b0, acc[0][0], 0, 0, 0);
        acc[1][0] = __builtin_amdgcn_mfma_f32_16x16x32_bf16(a1, b0, acc[1][0], 0, 0, 0);
        acc[0][1] = __builtin_amdgcn_mfma_f32_16x16x32_bf16(a0, b1, acc[0][1], 0, 0, 0);
        acc[1][1] = __builtin_amdgcn_mfma_f32_16x16x32_bf16(a1, b1, acc[1][1], 0, 0, 0);
    }
    float* pp = part + (size_t)by * 262144;
#pragma unroll
    for (int mt = 0; mt < 2; ++mt)
#pragma unroll
        for (int j = 0; j < 2; ++j)
#pragma unroll
            for (int r = 0; r < 4; ++r)
                pp[(m0 + mt * 16 + hi * 4 + r) * 128 + wid * 32 + j * 16 + lo] = acc[mt][j][r];
}

__global__ __launch_bounds__(256) void fc1_reduce_kernel(
    const float* __restrict__ part, const float* __restrict__ bias,
    float* __restrict__ outp)
{
    int idx = blockIdx.x * 256 + threadIdx.x;   // < 262144
    float s = 0.f;
#pragma unroll
    for (int ks = 0; ks < 4; ++ks) s += part[ks * 262144 + idx];
    outp[idx] = fmaxf(s + bias[idx & 127], 0.f);
}

// ---- fc2 + sigmoid*2pi -> angles[2048,10] ----
__global__ __launch_bounds__(256) void fc2_kernel(
    const float* __restrict__ h, const float* __restrict__ w,
    const float* __restrict__ bias, float* __restrict__ ang)
{
    int idx = blockIdx.x * 256 + threadIdx.x;
    if (idx >= 20480) return;
    int b = idx / 10, n = idx % 10;
    const float* hp = h + b * 128;
    const float* wp = w + n * 128;
    float s = bias[n];
    for (int k = 0; k < 128; ++k) s = fmaf(hp[k], wp[k], s);
    ang[idx] = 6.28318530718f / (1.f + expf(-s));
}

// ---------------- quantum circuit + <Y_k> + log_softmax ----------------
__device__ __forceinline__ void apply_rot(float2* s, int p, float phi, float th,
                                          float om, int tid)
{
    float c, sn; sincosf(0.5f * th, &sn, &c);
    float A = 0.5f * (phi + om), Bv = 0.5f * (phi - om);
    float cA, sA; sincosf(A, &sA, &cA);
    float cB, sB; sincosf(Bv, &sB, &cB);
    float2 m00 = make_float2(cA * c, -sA * c);
    float2 m01 = make_float2(-cB * sn, -sB * sn);
    float2 m10 = make_float2(cB * sn, -sB * sn);
    float2 m11 = make_float2(cA * c, sA * c);
    for (int q = tid; q < 512; q += 256) {
        int i0 = ((q >> p) << (p + 1)) | (q & ((1 << p) - 1));
        int i1 = i0 | (1 << p);
        float2 aa = s[i0], bb = s[i1];
        s[i0] = make_float2(m00.x * aa.x - m00.y * aa.y + m01.x * bb.x - m01.y * bb.y,
                            m00.x * aa.y + m00.y * aa.x + m01.x * bb.y + m01.y * bb.x);
        s[i1] = make_float2(m10.x * aa.x - m10.y * aa.y + m11.x * bb.x - m11.y * bb.y,
                            m10.x * aa.y + m10.y * aa.x + m11.x * bb.y + m11.y * bb.x);
    }
}

__global__ __launch_bounds__(256) void quantum_kernel(
    const float* __restrict__ ang, const float* __restrict__ theta0,
    const float* __restrict__ theta_rz, const float* __restrict__ theta_ps,
    const float* __restrict__ rot_p, float* __restrict__ out)
{
    __shared__ float2 s[1024];
    __shared__ float red[40];
    int b = blockIdx.x;
    int tid = threadIdx.x;

    float a[10];
#pragma unroll
    for (int k = 0; k < 10; ++k) a[k] = ang[b * 10 + k];
    float th[10];
#pragma unroll
    for (int k = 0; k < 10; ++k) th[k] = theta0[k] + a[k];
    th[1] += a[1];
    th[5] -= 0.78539816339745f;   // RX(-pi/4) on wire 5

    float2 v[10][2];
#pragma unroll
    for (int k = 0; k < 10; ++k) {
        float c, sn; sincosf(0.5f * th[k], &sn, &c);
        v[k][0] = make_float2(c, 0.f);
        v[k][1] = make_float2(0.f, -sn);
    }
    { float c, sn; sincosf(0.5f * a[2], &sn, &c);
      float2 v0 = v[2][0], v1 = v[2][1];
      v[2][0] = make_float2(c * v0.x - sn * v1.x, c * v0.y - sn * v1.y);
      v[2][1] = make_float2(sn * v0.x + c * v1.x, sn * v0.y + c * v1.y); }
    { float c, sn; sincosf(0.5f * a[3], &sn, &c);
      v[3][0] = cmul(v[3][0], make_float2(c, -sn));
      v[3][1] = cmul(v[3][1], make_float2(c, sn)); }
    { float2 t = v[4][1]; v[4][1] = make_float2(-t.y, t.x); }
    { const float r = 0.70710678118655f;
      float2 t = v[5][1]; v[5][1] = make_float2(r * (t.x - t.y), r * (t.x + t.y)); }
    { float c, sn; sincosf(0.5f * theta_rz[0], &sn, &c);
      v[6][0] = cmul(v[6][0], make_float2(c, -sn));
      v[6][1] = cmul(v[6][1], make_float2(c, sn)); }
    { float2 p = v[7][0], q = v[7][1];
      v[7][0] = make_float2(0.5f * ((p.x - p.y) + (q.x + q.y)),
                            0.5f * ((p.x + p.y) + (q.y - q.x)));
      v[7][1] = make_float2(0.5f * ((p.x + p.y) + (q.x - q.y)),
                            0.5f * ((p.y - p.x) + (q.x + q.y))); }

    // product state init — compile-time indices only (no scratch)
    for (int i = tid; i < 1024; i += 256) {
        float2 c = ((i >> 9) & 1) ? v[0][1] : v[0][0];
#pragma unroll
        for (int k = 1; k < 10; ++k) {
            float2 vk = ((i >> (9 - k)) & 1) ? v[k][1] : v[k][0];
            c = cmul(c, vk);
        }
        s[i] = c;
    }
    __syncthreads();

    for (int i = tid; i < 1024; i += 256)
        if (((i >> 9) & 1) && ((i >> 4) & 1)) { s[i].x = -s[i].x; s[i].y = -s[i].y; }
    __syncthreads();
    { int j = tid;
      int i0 = 512 | ((j >> 4) << 5) | (j & 15);
      int i1 = i0 | 16;
      float2 t0 = s[i0], t1 = s[i1];
      s[i0] = t1; s[i1] = t0; }
    __syncthreads();
    { int j = tid;
      int i0 = 512 | ((j >> 4) << 5) | (j & 15);
      int i1 = i0 | 16;
      float2 t0 = s[i0], t1 = s[i1];
      s[i0] = make_float2(t1.y, -t1.x);
      s[i1] = make_float2(-t0.y, t0.x); }
    __syncthreads();
    { int j = tid;
      int i0 = (j & 1) | (((j >> 1) & 15) << 2) | (((j >> 5) & 7) << 7) | 64;
      int i1 = i0 | 2;
      float2 t0 = s[i0], t1 = s[i1];
      s[i0] = make_float2(t1.y, -t1.x);
      s[i1] = make_float2(-t0.y, t0.x); }
    __syncthreads();
    { int j = tid;
      int i0 = (j & 63) | 128 | (((j >> 6) & 3) << 8);
      int i1 = i0 ^ 0xC0;
      float2 t0 = s[i0], t1 = s[i1];
      s[i0] = t1; s[i1] = t0; }
    __syncthreads();
    if (tid < 128) {
      int j = tid;
      int i0 = (j & 7) | 16 | 32 | (((j >> 3) & 15) << 6);
      int i1 = i0 ^ 0x18;
      float2 t0 = s[i0], t1 = s[i1];
      s[i0] = t1; s[i1] = t0; }
    __syncthreads();
    if (tid < 128) {
      int j = tid;
      int i0 = (j & 1) | 2 | (((j >> 1) & 3) << 2) | 16 | (((j >> 3) & 15) << 5);
      int i1 = i0 | 512;
      float2 t0 = s[i0], t1 = s[i1];
      s[i0] = t1; s[i1] = t0; }
    __syncthreads();
    { float c1, s1; sincosf(theta_ps[0], &s1, &c1);
      float c2, s2; sincosf(a[7], &s2, &c2);
      float2 p1 = make_float2(c1, s1), p2 = make_float2(c2, s2);
      for (int i = tid; i < 1024; i += 256) {
          float2 t = s[i];
          if ((i >> 1) & 1) t = cmul(t, p1);
          if ((i >> 2) & 1) t = cmul(t, p2);
          s[i] = t;
      } }
    __syncthreads();
    apply_rot(s, 5, rot_p[0], rot_p[1], rot_p[2], tid);
    __syncthreads();
    apply_rot(s, 4, a[6], a[7], a[8], tid);
    __syncthreads();

    int wave = tid >> 6;
    for (int k = 0; k < 10; ++k) {
        int p = 9 - k;
        float part = 0.f;
        for (int q = tid; q < 512; q += 256) {
            int i0 = ((q >> p) << (p + 1)) | (q & ((1 << p) - 1));
            int i1 = i0 | (1 << p);
            float2 aa = s[i0], bb = s[i1];
            part += aa.x * bb.y - aa.y * bb.x;
        }
        part *= 2.f;
#pragma unroll
        for (int off = 32; off > 0; off >>= 1)
            part += __shfl_down(part, off, 64);
        if ((tid & 63) == 0) red[k * 4 + wave] = part;
    }
    __syncthreads();
    if (tid == 0) {
        float ev[10];
        float mx = -1e30f;
#pragma unroll
        for (int k = 0; k < 10; ++k) {
            ev[k] = red[k * 4] + red[k * 4 + 1] + red[k * 4 + 2] + red[k * 4 + 3];
            mx = fmaxf(mx, ev[k]);
        }
        float sum = 0.f;
#pragma unroll
        for (int k = 0; k < 10; ++k) sum += expf(ev[k] - mx);
        float lse = mx + logf(sum);
#pragma unroll
        for (int k = 0; k < 10; ++k) out[b * 10 + k] = ev[k] - lse;
    }
}

extern "C" void kernel_launch(void* const* d_in, const int* in_sizes, int n_in,
                              void* d_out, int out_size, void* d_ws, size_t ws_size,
                              hipStream_t stream)
{
    (void)in_sizes; (void)n_in; (void)out_size; (void)ws_size;
    const float* x    = (const float*)d_in[0];
    const float* c1w  = (const float*)d_in[1];
    const float* c1b  = (const float*)d_in[2];
    const float* c2w  = (const float*)d_in[3];
    const float* c2b  = (const float*)d_in[4];
    const float* f1w  = (const float*)d_in[5];
    const float* f1b  = (const float*)d_in[6];
    const float* f2w  = (const float*)d_in[7];
    const float* f2b  = (const float*)d_in[8];
    const float* th0  = (const float*)d_in[9];
    const float* trz  = (const float*)d_in[10];
    const float* tps  = (const float*)d_in[11];
    const float* rotp = (const float*)d_in[12];
    float* out = (float*)d_out;

    char* ws = (char*)d_ws;
    ushort* h1b    = (ushort*)(ws);                       // 88,604,672 B
    ushort* pooled = (ushort*)(ws + 88604672);            // 37,748,736 B
    ushort* wt2    = (ushort*)(ws + 126353408);           //     36,864 B
    ushort* wf1    = (ushort*)(ws + 126390272);           //  2,359,296 B
    float*  part   = (float*)(ws + 128749568);            //  4,194,304 B
    float*  fc1o   = (float*)(ws + 132943872);            //  1,048,576 B
    float*  ang    = (float*)(ws + 133992448);            //     81,920 B

    prep_kernel<<<4680, 256, 0, stream>>>(c2w, f1w, wt2, wf1);
    conv1_kernel<<<21632, 256, 0, stream>>>(x, c1w, c1b, h1b);
    conv2_persist<<<256, 384, 0, stream>>>(h1b, wt2, c2b, pooled);
    fc1_mfma<<<dim3(64, 4), 256, 0, stream>>>(pooled, wf1, part);
    fc1_reduce_kernel<<<1024, 256, 0, stream>>>(part, f1b, fc1o);
    fc2_kernel<<<80, 256, 0, stream>>>(fc1o, f2w, f2b, ang);
    quantum_kernel<<<2048, 256, 0, stream>>>(ang, th0, trz, tps, rotp, out);
}